// Round 3
// baseline (1546.390 us; speedup 1.0000x reference)
//
#include <hip/hip_runtime.h>
#include <hip/hip_bf16.h>

typedef __attribute__((ext_vector_type(8))) short short8;
typedef __attribute__((ext_vector_type(4))) float floatx4;

using bf16 = __hip_bfloat16;

__device__ __forceinline__ void cp16_g2l(bf16* lds, const bf16* g) {
  __builtin_amdgcn_global_load_lds(
      (const __attribute__((address_space(1))) unsigned int*)g,
      (__attribute__((address_space(3))) unsigned int*)lds,
      16, 0, 0);
}

__device__ __forceinline__ float gelu_exact(float x) {
  return 0.5f * x * (1.0f + erff(x * 0.70710678118654752f));
}

// ---------------------------------------------------------------------------
// 256x256 tile GEMM, BK=32, 8 waves (2Mx4N), mfma_f32_16x16x32_bf16.
// LDS: 4-deep ring of K-tiles (A 256x32 + B 256x32 = 32 KiB each) = 128 KiB.
// Race-free deep pipeline:
//   - tile t+3 is staged (global_load_lds) into buf[(t+3)&3], which held tile
//     t-1; the barrier ending tile t-1 sealed all reads of it. No W/R race.
//   - counted s_waitcnt vmcnt(8) at end of tile t: per-thread ledger is 4
//     loads/tile, issue order monotone, so 8 outstanding == tiles t+2,t+3 in
//     flight and tile t+1 fully landed. Never drains to 0 mid-loop (T4).
//   - one s_barrier per K-tile, after the counted wait.
// Swizzle (T2, rule #21): logical 16B slot u of row r lives at physical slot
// u ^ ((r>>1)&3); applied by pre-swizzling the GLOBAL source (linear
// global_load_lds dest) and XORing the ds_read address. 16 lanes reading one
// k-column across 16 rows land on all 32 banks -> 2-way (free, m136).
// MODE 0: out bf16 = acc + bias
// MODE 1: out f32  = acc * scale
// MODE 2: out bf16 = acc
// MODE 3: out f32  = acc + bias + resid   (resid may alias out)
// MODE 4: out bf16 = gelu(acc + bias)
// Requires K % 32 == 0 and K >= 96 (all call sites: 768/2048/3072).
// ---------------------------------------------------------------------------
template<int MODE>
__global__ __launch_bounds__(512)
void gemm256(const bf16* __restrict__ A, long sAb, long lda,
             const bf16* __restrict__ Bt, long sBb, long ldb,
             const float* __restrict__ bias,
             const float* __restrict__ resid,
             void* __restrict__ out, long sOb,
             int N, int K, float scale)
{
  __shared__ __attribute__((aligned(16))) bf16 sA[4][256 * 32];  // 64 KiB
  __shared__ __attribute__((aligned(16))) bf16 sB[4][256 * 32];  // 64 KiB

  const int tid = threadIdx.x;
  const int l = tid & 63, w = tid >> 6;
  const int bz = blockIdx.z;
  const long row0 = (long)blockIdx.x * 256;
  const long col0 = (long)blockIdx.y * 256;
  const bf16* Ab = A + (long)bz * sAb + row0 * lda;
  const bf16* Bb = Bt + (long)bz * sBb + col0 * ldb;

  const int wr = w >> 2, wc = w & 3;   // wave tile: rows wr*128, cols wc*64
  const int g = l >> 4, t = l & 15;

  floatx4 acc[8][4];
  #pragma unroll
  for (int i = 0; i < 8; ++i)
    #pragma unroll
    for (int j = 0; j < 4; ++j)
      acc[i][j] = (floatx4){0.f, 0.f, 0.f, 0.f};

  // per-thread staging coordinates: 2 A-slots + 2 B-slots (16B each)
  // linear slot L = tid + j*512 ; row r = L>>2 ; logical col u = L&3 ;
  // global source col = u ^ ((r>>1)&3)  (inverse swizzle on the source)
  int srow[2], scol[2];
  #pragma unroll
  for (int j = 0; j < 2; ++j) {
    const int L = tid + j * 512;
    srow[j] = L >> 2;
    scol[j] = ((L & 3) ^ ((srow[j] >> 1) & 3)) << 3;  // element offset
  }

  auto stage = [&](int kt) {
    const int b = kt & 3;
    const long kb = (long)kt * 32;
    #pragma unroll
    for (int j = 0; j < 2; ++j)
      cp16_g2l(&sA[b][(tid + j * 512) * 8],
               Ab + (long)srow[j] * lda + kb + scol[j]);
    #pragma unroll
    for (int j = 0; j < 2; ++j)
      cp16_g2l(&sB[b][(tid + j * 512) * 8],
               Bb + (long)srow[j] * ldb + kb + scol[j]);
  };

  // ds_read offsets (loop-invariant): swizzled fragment addresses
  int aoff[8], boff[4];
  #pragma unroll
  for (int mi = 0; mi < 8; ++mi) {
    const int row = wr * 128 + mi * 16 + t;
    aoff[mi] = row * 32 + ((g ^ ((row >> 1) & 3)) << 3);
  }
  #pragma unroll
  for (int ni = 0; ni < 4; ++ni) {
    const int row = wc * 64 + ni * 16 + t;
    boff[ni] = row * 32 + ((g ^ ((row >> 1) & 3)) << 3);
  }

  const int nt = K >> 5;

  // prologue: stage tiles 0,1,2 (12 loads); wait tile 0 (8 stay in flight)
  stage(0);
  stage(1);
  stage(2);
  asm volatile("s_waitcnt vmcnt(8)" ::: "memory");
  asm volatile("s_barrier" ::: "memory");
  __builtin_amdgcn_sched_barrier(0);

  for (int kt = 0; kt < nt; ++kt) {
    if (kt + 4 <= nt) stage(kt + 3);     // into buf of tile kt-1 (sealed)
    __builtin_amdgcn_sched_barrier(0);   // pin stage issue before the wait

    const bf16* tA = sA[kt & 3];
    const bf16* tB = sB[kt & 3];
    short8 a[8], bfr[4];
    #pragma unroll
    for (int mi = 0; mi < 8; ++mi) a[mi] = *(const short8*)(tA + aoff[mi]);
    #pragma unroll
    for (int ni = 0; ni < 4; ++ni) bfr[ni] = *(const short8*)(tB + boff[ni]);

    __builtin_amdgcn_s_setprio(1);
    #pragma unroll
    for (int mi = 0; mi < 8; ++mi)
      #pragma unroll
      for (int ni = 0; ni < 4; ++ni)
        acc[mi][ni] = __builtin_amdgcn_mfma_f32_16x16x32_bf16(
            a[mi], bfr[ni], acc[mi][ni], 0, 0, 0);
    __builtin_amdgcn_s_setprio(0);

    // counted boundary wait: tile kt+1 landed, later tiles stay in flight
    if (kt + 4 <= nt) {
      asm volatile("s_waitcnt vmcnt(8)" ::: "memory");
    } else if (kt + 3 == nt) {
      asm volatile("s_waitcnt vmcnt(4)" ::: "memory");
    } else if (kt + 2 == nt) {
      asm volatile("s_waitcnt vmcnt(0)" ::: "memory");
    }
    if (kt + 1 < nt) {
      asm volatile("s_barrier" ::: "memory");
      __builtin_amdgcn_sched_barrier(0);
    }
  }

  // ---- epilogue: C/D layout col = lane&15, row = (lane>>4)*4 + r [m89] ----
  const long orow0 = row0 + wr * 128 + g * 4;
  const long ocol0 = col0 + wc * 64 + t;

  if constexpr (MODE == 0 || MODE == 2 || MODE == 4) {
    bf16* O = (bf16*)out + (long)bz * sOb;
    #pragma unroll
    for (int ni = 0; ni < 4; ++ni) {
      const long cc = ocol0 + ni * 16;
      float bv = 0.f;
      if constexpr (MODE != 2) bv = bias[cc];
      #pragma unroll
      for (int mi = 0; mi < 8; ++mi) {
        #pragma unroll
        for (int r = 0; r < 4; ++r) {
          float vv = acc[mi][ni][r] + bv;
          if constexpr (MODE == 4) vv = gelu_exact(vv);
          O[(orow0 + mi * 16 + r) * (long)N + cc] = __float2bfloat16(vv);
        }
      }
    }
  } else if constexpr (MODE == 1) {
    float* O = (float*)out + (long)bz * sOb;
    #pragma unroll
    for (int ni = 0; ni < 4; ++ni) {
      const long cc = ocol0 + ni * 16;
      #pragma unroll
      for (int mi = 0; mi < 8; ++mi)
        #pragma unroll
        for (int r = 0; r < 4; ++r)
          O[(orow0 + mi * 16 + r) * (long)N + cc] = acc[mi][ni][r] * scale;
    }
  } else {  // MODE 3
    float* O = (float*)out;
    #pragma unroll
    for (int ni = 0; ni < 4; ++ni) {
      const long cc = ocol0 + ni * 16;
      const float bv = bias[cc];
      #pragma unroll
      for (int mi = 0; mi < 8; ++mi) {
        #pragma unroll
        for (int r = 0; r < 4; ++r) {
          const long idx = (orow0 + mi * 16 + r) * (long)N + cc;
          O[idx] = acc[mi][ni][r] + bv + resid[idx];
        }
      }
    }
  }
}

// row LayerNorm over D=768, fp32 in -> bf16 out
__global__ __launch_bounds__(256)
void ln_kernel(const float* __restrict__ X, const float* __restrict__ G,
               const float* __restrict__ Bv, bf16* __restrict__ H)
{
  const int tid = threadIdx.x;
  const long row = blockIdx.x;
  const float* xr = X + row * 768;
  const float v0 = xr[tid], v1 = xr[tid + 256], v2 = xr[tid + 512];
  float s = v0 + v1 + v2;
  float s2 = v0 * v0 + v1 * v1 + v2 * v2;
  #pragma unroll
  for (int o = 32; o > 0; o >>= 1) {
    s += __shfl_xor(s, o);
    s2 += __shfl_xor(s2, o);
  }
  __shared__ float red[8];
  const int w = tid >> 6, l = tid & 63;
  if (l == 0) { red[w] = s; red[w + 4] = s2; }
  __syncthreads();
  s = red[0] + red[1] + red[2] + red[3];
  s2 = red[4] + red[5] + red[6] + red[7];
  const float mu = s * (1.f / 768.f);
  const float var = s2 * (1.f / 768.f) - mu * mu;
  const float rstd = rsqrtf(var + 1e-5f);
  bf16* hr = H + row * 768;
  hr[tid]       = __float2bfloat16((v0 - mu) * rstd * G[tid]       + Bv[tid]);
  hr[tid + 256] = __float2bfloat16((v1 - mu) * rstd * G[tid + 256] + Bv[tid + 256]);
  hr[tid + 512] = __float2bfloat16((v2 - mu) * rstd * G[tid + 512] + Bv[tid + 512]);
}

// row softmax over 2048 keys, fp32 scores -> bf16 probs
__global__ __launch_bounds__(256)
void softmax_kernel(const float* __restrict__ S, bf16* __restrict__ P)
{
  const int tid = threadIdx.x;
  const long row = blockIdx.x;
  const float* sr = S + row * 2048;
  float v[8];
  float mx = -1e30f;
  #pragma unroll
  for (int j = 0; j < 8; ++j) { v[j] = sr[tid + 256 * j]; mx = fmaxf(mx, v[j]); }
  #pragma unroll
  for (int o = 32; o > 0; o >>= 1) mx = fmaxf(mx, __shfl_xor(mx, o));
  __shared__ float red[4];
  const int w = tid >> 6, l = tid & 63;
  if (l == 0) red[w] = mx;
  __syncthreads();
  mx = fmaxf(fmaxf(red[0], red[1]), fmaxf(red[2], red[3]));
  float sum = 0.f;
  #pragma unroll
  for (int j = 0; j < 8; ++j) { v[j] = __expf(v[j] - mx); sum += v[j]; }
  #pragma unroll
  for (int o = 32; o > 0; o >>= 1) sum += __shfl_xor(sum, o);
  __syncthreads();
  if (l == 0) red[w] = sum;
  __syncthreads();
  sum = red[0] + red[1] + red[2] + red[3];
  const float inv = 1.f / sum;
  bf16* pr = P + row * 2048;
  #pragma unroll
  for (int j = 0; j < 8; ++j) pr[tid + 256 * j] = __float2bfloat16(v[j] * inv);
}

// Wt[n][k] = bf16(W[k][n]) ; W fp32 [K][N]. block (32,8)
__global__ void transpose_w(const float* __restrict__ W, bf16* __restrict__ Wt,
                            int K, int N)
{
  __shared__ float tile[32][33];
  const int n0 = blockIdx.x * 32, k0 = blockIdx.y * 32;
  const int tx = threadIdx.x, ty = threadIdx.y;
  #pragma unroll
  for (int j = ty; j < 32; j += 8)
    tile[j][tx] = W[(long)(k0 + j) * N + n0 + tx];
  __syncthreads();
  #pragma unroll
  for (int j = ty; j < 32; j += 8)
    Wt[(long)(n0 + j) * K + k0 + tx] = __float2bfloat16(tile[tx][j]);
}

// Vt[b][d][s] = qkv[(b*2048+s)*2304 + 1536 + d]  (bf16 v-slice of fused qkv)
__global__ void transpose_v(const bf16* __restrict__ QKV, bf16* __restrict__ Vt)
{
  __shared__ bf16 tile[32][33];
  const int d0 = blockIdx.x * 32, s0 = blockIdx.y * 32, b = blockIdx.z;
  const int tx = threadIdx.x, ty = threadIdx.y;
  #pragma unroll
  for (int j = ty; j < 32; j += 8)
    tile[j][tx] = QKV[((long)b * 2048 + s0 + j) * 2304 + 1536 + d0 + tx];
  __syncthreads();
  #pragma unroll
  for (int j = ty; j < 32; j += 8)
    Vt[(long)b * 768 * 2048 + (long)(d0 + j) * 2048 + s0 + tx] = tile[tx][j];
}

// concat 3x768 fp32 biases
__global__ void concat3(const float* __restrict__ a, const float* __restrict__ b,
                        const float* __restrict__ c, float* __restrict__ o)
{
  const int i = threadIdx.x + blockIdx.x * 256;
  if (i < 768) { o[i] = a[i]; o[i + 768] = b[i]; o[i + 1536] = c[i]; }
}

extern "C" void kernel_launch(void* const* d_in, const int* in_sizes, int n_in,
                              void* d_out, int out_size, void* d_ws, size_t ws_size,
                              hipStream_t stream)
{
  const float* x     = (const float*)d_in[0];
  const float* ln1g  = (const float*)d_in[1];
  const float* ln1b  = (const float*)d_in[2];
  const float* ln2g  = (const float*)d_in[3];
  const float* ln2b  = (const float*)d_in[4];
  const float* Wq    = (const float*)d_in[5];
  const float* bq    = (const float*)d_in[6];
  const float* Wk    = (const float*)d_in[7];
  const float* bk    = (const float*)d_in[8];
  const float* Wv    = (const float*)d_in[9];
  const float* bvv   = (const float*)d_in[10];
  const float* Wo    = (const float*)d_in[11];
  const float* bo    = (const float*)d_in[12];
  const float* Wfc   = (const float*)d_in[13];
  const float* bfc   = (const float*)d_in[14];
  const float* Wproj = (const float*)d_in[15];
  const float* bproj = (const float*)d_in[16];
  float* out = (float*)d_out;

  constexpr int Bz = 8, S = 2048, D = 768, Hh = 3072, QKVN = 3 * D;
  constexpr long Mtot = (long)Bz * S;  // 16384

  char* ws = (char*)d_ws;
  size_t off = 0;
  auto alloc = [&](size_t bytes) -> char* {
    char* p = ws + off;
    off += (bytes + 255) & ~(size_t)255;
    return p;
  };
  bf16* wqkvT = (bf16*)alloc((size_t)QKVN * D * 2);
  bf16* woT   = (bf16*)alloc((size_t)D * D * 2);
  bf16* wfcT  = (bf16*)alloc((size_t)Hh * D * 2);
  bf16* wprT  = (bf16*)alloc((size_t)D * Hh * 2);
  float* bqkv = (float*)alloc((size_t)QKVN * 4);
  bf16* hb    = (bf16*)alloc((size_t)Mtot * D * 2);
  bf16* qkv   = (bf16*)alloc((size_t)Mtot * QKVN * 2);
  bf16* vtb   = (bf16*)alloc((size_t)Mtot * D * 2);
  bf16* yb    = (bf16*)alloc((size_t)Mtot * D * 2);

  int nbat = Bz;
  size_t region = (size_t)nbat * S * S * 6;              // scores f32 + attn bf16
  const size_t mbytes = (size_t)Mtot * Hh * 2;           // MLP hidden bf16
  if (region < mbytes) region = mbytes;
  if (off + region > ws_size) {                          // fallback: per-batch attention
    nbat = 1;
    region = mbytes;
  }
  char* reg = alloc(region);
  float* scores = (float*)reg;
  bf16* attn = (bf16*)(reg + (size_t)nbat * S * S * 4);
  bf16* mb = (bf16*)reg;  // aliases scores/attn (used after attention done)

  const dim3 tb(32, 8);

  // weight prep (bf16, [N][K]); q/k/v stacked into wqkvT rows 0/768/1536
  transpose_w<<<dim3(D / 32, D / 32), tb, 0, stream>>>(Wq, wqkvT, D, D);
  transpose_w<<<dim3(D / 32, D / 32), tb, 0, stream>>>(Wk, wqkvT + (size_t)D * D, D, D);
  transpose_w<<<dim3(D / 32, D / 32), tb, 0, stream>>>(Wv, wqkvT + 2 * (size_t)D * D, D, D);
  transpose_w<<<dim3(D / 32, D / 32), tb, 0, stream>>>(Wo, woT, D, D);
  transpose_w<<<dim3(Hh / 32, D / 32), tb, 0, stream>>>(Wfc, wfcT, D, Hh);
  transpose_w<<<dim3(D / 32, Hh / 32), tb, 0, stream>>>(Wproj, wprT, Hh, D);
  concat3<<<3, 256, 0, stream>>>(bq, bk, bvv, bqkv);

  // LN1 -> h (bf16)
  ln_kernel<<<(int)Mtot, 256, 0, stream>>>(x, ln1g, ln1b, hb);

  // fused QKV projection: [16384,768] @ [2304,768]^T -> [16384,2304]
  gemm256<0><<<dim3(Mtot / 256, QKVN / 256, 1), 512, 0, stream>>>(
      hb, 0, D, wqkvT, 0, D, bqkv, nullptr, qkv, 0, QKVN, D, 1.f);
  transpose_v<<<dim3(D / 32, S / 32, Bz), tb, 0, stream>>>(qkv, vtb);

  // attention: scores -> softmax -> PV, grouped by nbat batches
  const float sc = 0.03608439182435161f;  // 1/sqrt(768)
  for (int g0 = 0; g0 < Bz; g0 += nbat) {
    const bf16* qg  = qkv + (long)g0 * S * QKVN;          // q slice, lda=2304
    const bf16* kg  = qkv + (long)g0 * S * QKVN + D;      // k slice, ldb=2304
    const bf16* vtg = vtb + (long)g0 * D * S;
    bf16* yg = yb + (long)g0 * S * D;
    gemm256<1><<<dim3(S / 256, S / 256, nbat), 512, 0, stream>>>(
        qg, (long)S * QKVN, QKVN, kg, (long)S * QKVN, QKVN, nullptr, nullptr,
        scores, (long)S * S, S, D, sc);
    softmax_kernel<<<nbat * S, 256, 0, stream>>>(scores, attn);
    gemm256<2><<<dim3(S / 256, D / 256, nbat), 512, 0, stream>>>(
        attn, (long)S * S, S, vtg, (long)D * S, S, nullptr, nullptr,
        yg, (long)S * D, D, S, 1.f);
  }

  // out-projection + residual -> d_out (fp32)
  gemm256<3><<<dim3(Mtot / 256, D / 256, 1), 512, 0, stream>>>(
      yb, 0, D, woT, 0, D, bo, x, out, 0, D, D, 1.f);

  // LN2 -> h2 (bf16, reuse hb)
  ln_kernel<<<(int)Mtot, 256, 0, stream>>>(out, ln2g, ln2b, hb);

  // MLP: fc + exact GELU -> mb (bf16), then proj + residual (in-place on d_out)
  gemm256<4><<<dim3(Mtot / 256, Hh / 256, 1), 512, 0, stream>>>(
      hb, 0, D, wfcT, 0, D, bfc, nullptr, mb, 0, Hh, D, 1.f);
  gemm256<3><<<dim3(Mtot / 256, D / 256, 1), 512, 0, stream>>>(
      mb, 0, Hh, wprT, 0, Hh, bproj, out, out, 0, D, Hh, 1.f);
}

// Round 4
// 1258.491 us; speedup vs baseline: 1.2288x; 1.2288x over previous
//
#include <hip/hip_runtime.h>
#include <hip/hip_bf16.h>

typedef __attribute__((ext_vector_type(8))) short short8;
typedef __attribute__((ext_vector_type(4))) float floatx4;

using bf16 = __hip_bfloat16;

__device__ __forceinline__ void cp16_g2l(bf16* lds_p, const bf16* g) {
  __builtin_amdgcn_global_load_lds(
      (const __attribute__((address_space(1))) unsigned int*)g,
      (__attribute__((address_space(3))) unsigned int*)lds_p,
      16, 0, 0);
}

__device__ __forceinline__ float gelu_exact(float x) {
  return 0.5f * x * (1.0f + erff(x * 0.70710678118654752f));
}

// ---------------------------------------------------------------------------
// 256x256 tile GEMM, BK=64, 8 waves (2Mx4N), mfma_f32_16x16x32_bf16.
// m201-style 8-phase schedule. LDS panels: [slot][mat][half] of 128x64 bf16
// (16 KiB each, 8 panels = 128 KiB). Iter processes tiles t (slot0), t+1
// (slot1) in 8 phases; each phase: {ds_reads, 1 panel stage} -> barrier ->
// lgkmcnt(0) -> 16 MFMA (one C-quadrant x K=64) -> barrier.
// Quadrant order per tile: (0,0),(0,1),(1,1),(1,0); B frags stay in regs, so
// B panels die after ph2 (ph6), A panels after ph3 (ph7) -- every stage
// target below is sealed by the immediately preceding barrier:
//   ph1: A0(t+1)->s1  [A0(t-1) died prev ph7]   ph5: A0(t+2)->s0 [died ph3]
//   ph2: A1(t+1)->s1  [ " ]                     ph6: A1(t+2)->s0 [died ph3]
//   ph3: B0(t+2)->s0  [B0(t) died ph2]          ph7: B0(t+3)->s1 [died ph6]
//   ph4: B1(t+2)->s0  [ " ]                     ph8: B1(t+3)->s1 [ " ]
// vmcnt(4) at ph4 and ph8 only (outstanding = last 2 panel stages = 4 loads):
//   ph4: guarantees A(t+1) (ph1,2) + prev B(t+1) landed before ph5 reads.
//   ph8: guarantees t+2 (ph3..6) landed before next ph1 reads.
// Swizzle (T2, rule #21): 16B slot u of row r at physical u^(r&7); inverse-
// swizzled global source + swizzled ds_read; gload_lds dest stays linear.
// MODE 0: bf16 = acc+bias | 1: f32 = acc*scale | 2: bf16 = acc
// MODE 3: f32 = acc+bias+resid (may alias out) | 4: bf16 = gelu(acc+bias)
// Requires K % 128 == 0 (NT even). Call sites: K = 768 / 2048 / 3072.
// ---------------------------------------------------------------------------
template<int MODE>
__global__ __launch_bounds__(512)
void gemm256(const bf16* __restrict__ A, long sAb, long lda,
             const bf16* __restrict__ Bt, long sBb, long ldb,
             const float* __restrict__ bias,
             const float* __restrict__ resid,
             void* __restrict__ out, long sOb,
             int N, int K, float scale)
{
  constexpr int PANEL = 128 * 64;
  __shared__ __attribute__((aligned(16))) bf16 lds[8 * PANEL];  // 128 KiB

  const int tid = threadIdx.x;
  const int l = tid & 63, w = tid >> 6;
  const int bz = blockIdx.z;
  const long row0 = (long)blockIdx.x * 256;
  const long col0 = (long)blockIdx.y * 256;
  const bf16* Ab = A + (long)bz * sAb + row0 * lda;
  const bf16* Bb = Bt + (long)bz * sBb + col0 * ldb;

  const int wr = w >> 2, wc = w & 3;   // wave tile: rows wr*128, cols wc*64
  const int g = l >> 4, t = l & 15;
  const int t64 = t * 64;
  const int swz0 = ((0 * 4 + g) ^ (t & 7)) * 8;   // ks=0 swizzled col offset
  const int swz1 = ((1 * 4 + g) ^ (t & 7)) * 8;   // ks=1

  // staging per-thread invariants: 2 x 16B per panel stage
  long rowA[2], rowB[2];
  #pragma unroll
  for (int j = 0; j < 2; ++j) {
    const int L = tid + j * 512;
    const int prow = L >> 3;
    const int ul = ((L & 7) ^ (prow & 7)) * 8;    // inverse-swizzled src col
    rowA[j] = (long)prow * lda + ul;
    rowB[j] = (long)prow * ldb + ul;
  }

  auto stageP = [&](int slot, int mat, int half, int kt) {
    const bf16* srcb = mat ? Bb : Ab;
    const long ld = mat ? ldb : lda;
    bf16* dst = lds + (size_t)(slot * 4 + mat * 2 + half) * PANEL;
    const long hoff = (long)half * 128 * ld + (long)kt * 64;
    #pragma unroll
    for (int j = 0; j < 2; ++j)
      cp16_g2l(dst + (size_t)(tid + j * 512) * 8,
               srcb + (mat ? rowB[j] : rowA[j]) + hoff);
  };

  floatx4 acc[8][4];
  #pragma unroll
  for (int i = 0; i < 8; ++i)
    #pragma unroll
    for (int j = 0; j < 4; ++j)
      acc[i][j] = (floatx4){0.f, 0.f, 0.f, 0.f};

  short8 a[4][2];      // current A quadrant frags (reloaded ph1/ph3)
  short8 b[2][2][2];   // [qn][ni][ks], both qn sets live across the tile

#define READ_A(SLOT, QM) do {                                              \
    const bf16* _p = lds + (size_t)((SLOT) * 4 + wr) * PANEL + t64;        \
    _Pragma("unroll")                                                      \
    for (int mi = 0; mi < 4; ++mi) {                                       \
      a[mi][0] = *(const short8*)(_p + ((QM) * 64 + mi * 16) * 64 + swz0); \
      a[mi][1] = *(const short8*)(_p + ((QM) * 64 + mi * 16) * 64 + swz1); \
    } } while (0)

#define READ_B(SLOT, QN) do {                                              \
    const bf16* _p = lds + (size_t)((SLOT) * 4 + 2 + (wc >> 1)) * PANEL    \
                     + (wc & 1) * 64 * 64 + t64;                           \
    _Pragma("unroll")                                                      \
    for (int ni = 0; ni < 2; ++ni) {                                       \
      b[QN][ni][0] = *(const short8*)(_p + ((QN) * 32 + ni * 16) * 64 + swz0); \
      b[QN][ni][1] = *(const short8*)(_p + ((QN) * 32 + ni * 16) * 64 + swz1); \
    } } while (0)

#define PHASE_MID() do {                                                   \
    __builtin_amdgcn_sched_barrier(0);                                     \
    asm volatile("s_barrier" ::: "memory");                                \
    asm volatile("s_waitcnt lgkmcnt(0)" ::: "memory");                     \
    __builtin_amdgcn_sched_barrier(0); } while (0)

#define PHASE_END() do {                                                   \
    __builtin_amdgcn_sched_barrier(0);                                     \
    asm volatile("s_barrier" ::: "memory");                                \
    __builtin_amdgcn_sched_barrier(0); } while (0)

#define MFMA_QUAD(QM, QN) do {                                             \
    __builtin_amdgcn_s_setprio(1);                                         \
    _Pragma("unroll")                                                      \
    for (int mi = 0; mi < 4; ++mi)                                         \
      _Pragma("unroll")                                                    \
      for (int ni = 0; ni < 2; ++ni)                                       \
        _Pragma("unroll")                                                  \
        for (int ks = 0; ks < 2; ++ks)                                     \
          acc[(QM) * 4 + mi][(QN) * 2 + ni] =                              \
              __builtin_amdgcn_mfma_f32_16x16x32_bf16(                     \
                  a[mi][ks], b[QN][ni][ks],                                \
                  acc[(QM) * 4 + mi][(QN) * 2 + ni], 0, 0, 0);             \
    __builtin_amdgcn_s_setprio(0); } while (0)

  const int NT = K >> 6;

  // prologue: tile0 full (8 loads) + tile1's B panels (4 loads)
  stageP(0, 0, 0, 0); stageP(0, 0, 1, 0);
  stageP(0, 1, 0, 0); stageP(0, 1, 1, 0);
  stageP(1, 1, 0, 1); stageP(1, 1, 1, 1);
  asm volatile("s_waitcnt vmcnt(4)" ::: "memory");  // tile0 landed
  asm volatile("s_barrier" ::: "memory");
  __builtin_amdgcn_sched_barrier(0);

  for (int tt = 0; tt < NT; tt += 2) {
    const bool s2 = (tt + 2 < NT), s3 = (tt + 3 < NT);
    // ---- tile tt (slot 0) ----
    // ph1
    READ_A(0, 0); READ_B(0, 0);
    stageP(1, 0, 0, tt + 1);
    PHASE_MID(); MFMA_QUAD(0, 0); PHASE_END();
    // ph2
    READ_B(0, 1);
    stageP(1, 0, 1, tt + 1);
    PHASE_MID(); MFMA_QUAD(0, 1); PHASE_END();
    // ph3
    READ_A(0, 1);
    if (s2) stageP(0, 1, 0, tt + 2);
    PHASE_MID(); MFMA_QUAD(1, 1); PHASE_END();
    // ph4
    if (s2) {
      stageP(0, 1, 1, tt + 2);
      asm volatile("s_waitcnt vmcnt(4)" ::: "memory");
    } else {
      asm volatile("s_waitcnt vmcnt(0)" ::: "memory");
    }
    PHASE_MID(); MFMA_QUAD(1, 0); PHASE_END();
    // ---- tile tt+1 (slot 1) ----
    // ph5
    READ_A(1, 0); READ_B(1, 0);
    if (s2) stageP(0, 0, 0, tt + 2);
    PHASE_MID(); MFMA_QUAD(0, 0); PHASE_END();
    // ph6
    READ_B(1, 1);
    if (s2) stageP(0, 0, 1, tt + 2);
    PHASE_MID(); MFMA_QUAD(0, 1); PHASE_END();
    // ph7
    READ_A(1, 1);
    if (s3) stageP(1, 1, 0, tt + 3);
    PHASE_MID(); MFMA_QUAD(1, 1); PHASE_END();
    // ph8
    if (s3) {
      stageP(1, 1, 1, tt + 3);
      asm volatile("s_waitcnt vmcnt(4)" ::: "memory");
    } else {
      asm volatile("s_waitcnt vmcnt(0)" ::: "memory");
    }
    PHASE_MID(); MFMA_QUAD(1, 0); PHASE_END();
  }

#undef READ_A
#undef READ_B
#undef PHASE_MID
#undef PHASE_END
#undef MFMA_QUAD

  // ---- epilogue: C/D layout col = lane&15, row = (lane>>4)*4 + r [m89] ----
  const long orow0 = row0 + wr * 128 + g * 4;
  const long ocol0 = col0 + wc * 64 + t;

  if constexpr (MODE == 0 || MODE == 2 || MODE == 4) {
    bf16* O = (bf16*)out + (long)bz * sOb;
    #pragma unroll
    for (int ni = 0; ni < 4; ++ni) {
      const long cc = ocol0 + ni * 16;
      float bv = 0.f;
      if constexpr (MODE != 2) bv = bias[cc];
      #pragma unroll
      for (int mi = 0; mi < 8; ++mi) {
        #pragma unroll
        for (int r = 0; r < 4; ++r) {
          float vv = acc[mi][ni][r] + bv;
          if constexpr (MODE == 4) vv = gelu_exact(vv);
          O[(orow0 + mi * 16 + r) * (long)N + cc] = __float2bfloat16(vv);
        }
      }
    }
  } else if constexpr (MODE == 1) {
    float* O = (float*)out + (long)bz * sOb;
    #pragma unroll
    for (int ni = 0; ni < 4; ++ni) {
      const long cc = ocol0 + ni * 16;
      #pragma unroll
      for (int mi = 0; mi < 8; ++mi)
        #pragma unroll
        for (int r = 0; r < 4; ++r)
          O[(orow0 + mi * 16 + r) * (long)N + cc] = acc[mi][ni][r] * scale;
    }
  } else {  // MODE 3
    float* O = (float*)out;
    #pragma unroll
    for (int ni = 0; ni < 4; ++ni) {
      const long cc = ocol0 + ni * 16;
      const float bv = bias[cc];
      #pragma unroll
      for (int mi = 0; mi < 8; ++mi) {
        #pragma unroll
        for (int r = 0; r < 4; ++r) {
          const long idx = (orow0 + mi * 16 + r) * (long)N + cc;
          O[idx] = acc[mi][ni][r] + bv + resid[idx];
        }
      }
    }
  }
}

// row LayerNorm over D=768, fp32 in -> bf16 out
__global__ __launch_bounds__(256)
void ln_kernel(const float* __restrict__ X, const float* __restrict__ G,
               const float* __restrict__ Bv, bf16* __restrict__ H)
{
  const int tid = threadIdx.x;
  const long row = blockIdx.x;
  const float* xr = X + row * 768;
  const float v0 = xr[tid], v1 = xr[tid + 256], v2 = xr[tid + 512];
  float s = v0 + v1 + v2;
  float s2 = v0 * v0 + v1 * v1 + v2 * v2;
  #pragma unroll
  for (int o = 32; o > 0; o >>= 1) {
    s += __shfl_xor(s, o);
    s2 += __shfl_xor(s2, o);
  }
  __shared__ float red[8];
  const int w = tid >> 6, l = tid & 63;
  if (l == 0) { red[w] = s; red[w + 4] = s2; }
  __syncthreads();
  s = red[0] + red[1] + red[2] + red[3];
  s2 = red[4] + red[5] + red[6] + red[7];
  const float mu = s * (1.f / 768.f);
  const float var = s2 * (1.f / 768.f) - mu * mu;
  const float rstd = rsqrtf(var + 1e-5f);
  bf16* hr = H + row * 768;
  hr[tid]       = __float2bfloat16((v0 - mu) * rstd * G[tid]       + Bv[tid]);
  hr[tid + 256] = __float2bfloat16((v1 - mu) * rstd * G[tid + 256] + Bv[tid + 256]);
  hr[tid + 512] = __float2bfloat16((v2 - mu) * rstd * G[tid + 512] + Bv[tid + 512]);
}

// row softmax over 2048 keys, fp32 scores -> bf16 probs
__global__ __launch_bounds__(256)
void softmax_kernel(const float* __restrict__ S, bf16* __restrict__ P)
{
  const int tid = threadIdx.x;
  const long row = blockIdx.x;
  const float* sr = S + row * 2048;
  float v[8];
  float mx = -1e30f;
  #pragma unroll
  for (int j = 0; j < 8; ++j) { v[j] = sr[tid + 256 * j]; mx = fmaxf(mx, v[j]); }
  #pragma unroll
  for (int o = 32; o > 0; o >>= 1) mx = fmaxf(mx, __shfl_xor(mx, o));
  __shared__ float red[4];
  const int w = tid >> 6, l = tid & 63;
  if (l == 0) red[w] = mx;
  __syncthreads();
  mx = fmaxf(fmaxf(red[0], red[1]), fmaxf(red[2], red[3]));
  float sum = 0.f;
  #pragma unroll
  for (int j = 0; j < 8; ++j) { v[j] = __expf(v[j] - mx); sum += v[j]; }
  #pragma unroll
  for (int o = 32; o > 0; o >>= 1) sum += __shfl_xor(sum, o);
  __syncthreads();
  if (l == 0) red[w] = sum;
  __syncthreads();
  sum = red[0] + red[1] + red[2] + red[3];
  const float inv = 1.f / sum;
  bf16* pr = P + row * 2048;
  #pragma unroll
  for (int j = 0; j < 8; ++j) pr[tid + 256 * j] = __float2bfloat16(v[j] * inv);
}

// Wt[n][k] = bf16(W[k][n]) ; W fp32 [K][N]. block (32,8)
__global__ void transpose_w(const float* __restrict__ W, bf16* __restrict__ Wt,
                            int K, int N)
{
  __shared__ float tile[32][33];
  const int n0 = blockIdx.x * 32, k0 = blockIdx.y * 32;
  const int tx = threadIdx.x, ty = threadIdx.y;
  #pragma unroll
  for (int j = ty; j < 32; j += 8)
    tile[j][tx] = W[(long)(k0 + j) * N + n0 + tx];
  __syncthreads();
  #pragma unroll
  for (int j = ty; j < 32; j += 8)
    Wt[(long)(n0 + j) * K + k0 + tx] = __float2bfloat16(tile[tx][j]);
}

// Vt[b][d][s] = qkv[(b*2048+s)*2304 + 1536 + d]  (bf16 v-slice of fused qkv)
__global__ void transpose_v(const bf16* __restrict__ QKV, bf16* __restrict__ Vt)
{
  __shared__ bf16 tile[32][33];
  const int d0 = blockIdx.x * 32, s0 = blockIdx.y * 32, b = blockIdx.z;
  const int tx = threadIdx.x, ty = threadIdx.y;
  #pragma unroll
  for (int j = ty; j < 32; j += 8)
    tile[j][tx] = QKV[((long)b * 2048 + s0 + j) * 2304 + 1536 + d0 + tx];
  __syncthreads();
  #pragma unroll
  for (int j = ty; j < 32; j += 8)
    Vt[(long)b * 768 * 2048 + (long)(d0 + j) * 2048 + s0 + tx] = tile[tx][j];
}

// concat 3x768 fp32 biases
__global__ void concat3(const float* __restrict__ a, const float* __restrict__ b,
                        const float* __restrict__ c, float* __restrict__ o)
{
  const int i = threadIdx.x + blockIdx.x * 256;
  if (i < 768) { o[i] = a[i]; o[i + 768] = b[i]; o[i + 1536] = c[i]; }
}

extern "C" void kernel_launch(void* const* d_in, const int* in_sizes, int n_in,
                              void* d_out, int out_size, void* d_ws, size_t ws_size,
                              hipStream_t stream)
{
  const float* x     = (const float*)d_in[0];
  const float* ln1g  = (const float*)d_in[1];
  const float* ln1b  = (const float*)d_in[2];
  const float* ln2g  = (const float*)d_in[3];
  const float* ln2b  = (const float*)d_in[4];
  const float* Wq    = (const float*)d_in[5];
  const float* bq    = (const float*)d_in[6];
  const float* Wk    = (const float*)d_in[7];
  const float* bk    = (const float*)d_in[8];
  const float* Wv    = (const float*)d_in[9];
  const float* bvv   = (const float*)d_in[10];
  const float* Wo    = (const float*)d_in[11];
  const float* bo    = (const float*)d_in[12];
  const float* Wfc   = (const float*)d_in[13];
  const float* bfc   = (const float*)d_in[14];
  const float* Wproj = (const float*)d_in[15];
  const float* bproj = (const float*)d_in[16];
  float* out = (float*)d_out;

  constexpr int Bz = 8, S = 2048, D = 768, Hh = 3072, QKVN = 3 * D;
  constexpr long Mtot = (long)Bz * S;  // 16384

  char* ws = (char*)d_ws;
  size_t off = 0;
  auto alloc = [&](size_t bytes) -> char* {
    char* p = ws + off;
    off += (bytes + 255) & ~(size_t)255;
    return p;
  };
  bf16* wqkvT = (bf16*)alloc((size_t)QKVN * D * 2);
  bf16* woT   = (bf16*)alloc((size_t)D * D * 2);
  bf16* wfcT  = (bf16*)alloc((size_t)Hh * D * 2);
  bf16* wprT  = (bf16*)alloc((size_t)D * Hh * 2);
  float* bqkv = (float*)alloc((size_t)QKVN * 4);
  bf16* hb    = (bf16*)alloc((size_t)Mtot * D * 2);
  bf16* qkv   = (bf16*)alloc((size_t)Mtot * QKVN * 2);
  bf16* vtb   = (bf16*)alloc((size_t)Mtot * D * 2);
  bf16* yb    = (bf16*)alloc((size_t)Mtot * D * 2);

  int nbat = Bz;
  size_t region = (size_t)nbat * S * S * 6;              // scores f32 + attn bf16
  const size_t mbytes = (size_t)Mtot * Hh * 2;           // MLP hidden bf16
  if (region < mbytes) region = mbytes;
  if (off + region > ws_size) {                          // fallback: per-batch attention
    nbat = 1;
    region = mbytes;
  }
  char* reg = alloc(region);
  float* scores = (float*)reg;
  bf16* attn = (bf16*)(reg + (size_t)nbat * S * S * 4);
  bf16* mb = (bf16*)reg;  // aliases scores/attn (used after attention done)

  const dim3 tb(32, 8);

  // weight prep (bf16, [N][K]); q/k/v stacked into wqkvT rows 0/768/1536
  transpose_w<<<dim3(D / 32, D / 32), tb, 0, stream>>>(Wq, wqkvT, D, D);
  transpose_w<<<dim3(D / 32, D / 32), tb, 0, stream>>>(Wk, wqkvT + (size_t)D * D, D, D);
  transpose_w<<<dim3(D / 32, D / 32), tb, 0, stream>>>(Wv, wqkvT + 2 * (size_t)D * D, D, D);
  transpose_w<<<dim3(D / 32, D / 32), tb, 0, stream>>>(Wo, woT, D, D);
  transpose_w<<<dim3(Hh / 32, D / 32), tb, 0, stream>>>(Wfc, wfcT, D, Hh);
  transpose_w<<<dim3(D / 32, Hh / 32), tb, 0, stream>>>(Wproj, wprT, Hh, D);
  concat3<<<3, 256, 0, stream>>>(bq, bk, bvv, bqkv);

  // LN1 -> h (bf16)
  ln_kernel<<<(int)Mtot, 256, 0, stream>>>(x, ln1g, ln1b, hb);

  // fused QKV projection: [16384,768] @ [2304,768]^T -> [16384,2304]
  gemm256<0><<<dim3(Mtot / 256, QKVN / 256, 1), 512, 0, stream>>>(
      hb, 0, D, wqkvT, 0, D, bqkv, nullptr, qkv, 0, QKVN, D, 1.f);
  transpose_v<<<dim3(D / 32, S / 32, Bz), tb, 0, stream>>>(qkv, vtb);

  // attention: scores -> softmax -> PV, grouped by nbat batches
  const float sc = 0.03608439182435161f;  // 1/sqrt(768)
  for (int g0 = 0; g0 < Bz; g0 += nbat) {
    const bf16* qg  = qkv + (long)g0 * S * QKVN;          // q slice, lda=2304
    const bf16* kg  = qkv + (long)g0 * S * QKVN + D;      // k slice, ldb=2304
    const bf16* vtg = vtb + (long)g0 * D * S;
    bf16* yg = yb + (long)g0 * S * D;
    gemm256<1><<<dim3(S / 256, S / 256, nbat), 512, 0, stream>>>(
        qg, (long)S * QKVN, QKVN, kg, (long)S * QKVN, QKVN, nullptr, nullptr,
        scores, (long)S * S, S, D, sc);
    softmax_kernel<<<nbat * S, 256, 0, stream>>>(scores, attn);
    gemm256<2><<<dim3(S / 256, D / 256, nbat), 512, 0, stream>>>(
        attn, (long)S * S, S, vtg, (long)D * S, S, nullptr, nullptr,
        yg, (long)S * D, D, S, 1.f);
  }

  // out-projection + residual -> d_out (fp32)
  gemm256<3><<<dim3(Mtot / 256, D / 256, 1), 512, 0, stream>>>(
      yb, 0, D, woT, 0, D, bo, x, out, 0, D, D, 1.f);

  // LN2 -> h2 (bf16, reuse hb)
  ln_kernel<<<(int)Mtot, 256, 0, stream>>>(out, ln2g, ln2b, hb);

  // MLP: fc + exact GELU -> mb (bf16), then proj + residual (in-place on d_out)
  gemm256<4><<<dim3(Mtot / 256, Hh / 256, 1), 512, 0, stream>>>(
      hb, 0, D, wfcT, 0, D, bfc, nullptr, mb, 0, Hh, D, 1.f);
  gemm256<3><<<dim3(Mtot / 256, D / 256, 1), 512, 0, stream>>>(
      mb, 0, Hh, wprT, 0, Hh, bproj, out, out, 0, D, Hh, 1.f);
}

// Round 5
// 691.433 us; speedup vs baseline: 2.2365x; 1.8201x over previous
//
#include <hip/hip_runtime.h>
#include <hip/hip_bf16.h>

typedef __attribute__((ext_vector_type(8))) short short8;
typedef __attribute__((ext_vector_type(4))) float floatx4;

using bf16 = __hip_bfloat16;

__device__ __forceinline__ void cp16_g2l(bf16* lds_p, const bf16* g) {
  __builtin_amdgcn_global_load_lds(
      (const __attribute__((address_space(1))) unsigned int*)g,
      (__attribute__((address_space(3))) unsigned int*)lds_p,
      16, 0, 0);
}

__device__ __forceinline__ float gelu_exact(float x) {
  return 0.5f * x * (1.0f + erff(x * 0.70710678118654752f));
}

// ---------------------------------------------------------------------------
// r1 engine (proven best at these shapes: 32 KiB LDS -> ~3 blocks/CU of
// implicit cross-block overlap, m114) + T2 swizzle + lda/ldb + fused softmax.
// 128x128 tile, BK=32, 4 waves (2x2), mfma_f32_16x16x32_bf16, fp32 accum.
// C[M,N] = A[M,K] @ Bt[N,K]^T, batched via blockIdx.z.
// Swizzle (rule #21): 16B slot u of row r lives at physical u^((r>>1)&3).
// gload_lds dest stays lane-linear; source pre-swizzled; ds_read XORed.
// Quarter-wave bank check: 16 lanes (fixed g, t=0..15) hit slot-mod-8 =
// (t&1)*4 + (g^((t>>1)&3)) -> 8 distinct, 2-way = free (m136). Unswizzled
// was {g, g+4} only -> 8-way (the 9.4M conflicts of r1).
// MODE 0: out bf16 = acc + bias
// MODE 3: out f32  = acc + bias + resid (resid may alias out)
// MODE 4: out bf16 = gelu(acc + bias)
// MODE 5: out bf16 = acc / rsum[bz*rsS + row]          (PV with fused softmax)
// MODE 6: out bf16 = exp(acc*scale), atomicAdd row-sums into rsum (scores)
// ---------------------------------------------------------------------------
template<int MODE>
__global__ __launch_bounds__(256)
void gemm_bt(const bf16* __restrict__ A, long sAb, long lda,
             const bf16* __restrict__ Bt, long sBb, long ldb,
             const float* __restrict__ bias,
             const float* __restrict__ resid,
             float* __restrict__ rsum, long rsS,
             void* __restrict__ out, long sOb,
             int N, int K, float scale)
{
  __shared__ __attribute__((aligned(16))) bf16 sA[2][128 * 32];
  __shared__ __attribute__((aligned(16))) bf16 sB[2][128 * 32];

  const int tid = threadIdx.x;
  const int l = tid & 63, w = tid >> 6;
  const int bz = blockIdx.z;
  const long row0 = (long)blockIdx.x * 128;
  const long col0 = (long)blockIdx.y * 128;

  const bf16* Ab = A + (long)bz * sAb;
  const bf16* Bb = Bt + (long)bz * sBb;

  // staging: wave w covers rows [w*16, w*16+16) and [+64); 4 slots of 16B/row
  const int sr = (w << 4) + (l >> 2);               // 0..63
  const int kcs = (((l & 3) ^ ((sr >> 1) & 3)) << 3);  // inverse-swizzled src
  const int kcd = (l & 3) << 3;                     // lane-linear dest
  const bf16* gA = Ab + (row0 + sr) * lda + kcs;
  const bf16* gB = Bb + (col0 + sr) * ldb + kcs;
  bf16* lA = &sA[0][sr * 32 + kcd];
  bf16* lB = &sB[0][sr * 32 + kcd];
  const long skipA = 64 * lda, skipB = 64 * ldb;

  floatx4 acc[4][4];
  #pragma unroll
  for (int i = 0; i < 4; ++i)
    #pragma unroll
    for (int j = 0; j < 4; ++j)
      acc[i][j] = (floatx4){0.f, 0.f, 0.f, 0.f};

  const int wr = (w >> 1) & 1, wc = w & 1;
  const int g = l >> 4, t = l & 15;
  const int swz = (g ^ ((t >> 1) & 3)) << 3;        // swizzled ds_read slot
  const int aoff = (wr * 64 + t) * 32 + swz;
  const int boff = (wc * 64 + t) * 32 + swz;

  const int nt = K >> 5;

  // prologue: stage tile 0 into buf 0
  cp16_g2l(lA,           gA);
  cp16_g2l(lA + 64 * 32, gA + skipA);
  cp16_g2l(lB,           gB);
  cp16_g2l(lB + 64 * 32, gB + skipB);
  __syncthreads();   // drains vmcnt(0)

  for (int kt = 0; kt < nt; ++kt) {
    const int cur = kt & 1;
    if (kt + 1 < nt) {
      const long ko = (long)(kt + 1) << 5;
      bf16* dA = lA + (cur ^ 1) * (128 * 32);
      bf16* dB = lB + (cur ^ 1) * (128 * 32);
      cp16_g2l(dA,           gA + ko);
      cp16_g2l(dA + 64 * 32, gA + ko + skipA);
      cp16_g2l(dB,           gB + ko);
      cp16_g2l(dB + 64 * 32, gB + ko + skipB);
    }
    const bf16* cA = &sA[cur][0];
    const bf16* cB = &sB[cur][0];
    short8 a[4], b[4];
    #pragma unroll
    for (int m = 0; m < 4; ++m) a[m] = *(const short8*)(cA + aoff + m * 512);
    #pragma unroll
    for (int n = 0; n < 4; ++n) b[n] = *(const short8*)(cB + boff + n * 512);
    #pragma unroll
    for (int m = 0; m < 4; ++m)
      #pragma unroll
      for (int n = 0; n < 4; ++n)
        acc[m][n] = __builtin_amdgcn_mfma_f32_16x16x32_bf16(a[m], b[n], acc[m][n], 0, 0, 0);
    __syncthreads();   // drains this iter's prefetch + everyone's ds_reads
  }

  // epilogue: C/D layout col = lane&15, row = (lane>>4)*4 + r  [m89]
  const long orow = row0 + wr * 64 + (g << 2);
  const long ocol = col0 + wc * 64 + t;

  if constexpr (MODE == 0 || MODE == 4) {
    bf16* O = (bf16*)out + (long)bz * sOb;
    #pragma unroll
    for (int n = 0; n < 4; ++n) {
      const long cc = ocol + n * 16;
      const float bv = bias[cc];
      #pragma unroll
      for (int m = 0; m < 4; ++m) {
        #pragma unroll
        for (int r = 0; r < 4; ++r) {
          float vv = acc[m][n][r] + bv;
          if constexpr (MODE == 4) vv = gelu_exact(vv);
          O[(orow + m * 16 + r) * (long)N + cc] = __float2bfloat16(vv);
        }
      }
    }
  } else if constexpr (MODE == 3) {
    float* O = (float*)out;
    #pragma unroll
    for (int n = 0; n < 4; ++n) {
      const long cc = ocol + n * 16;
      const float bv = bias[cc];
      #pragma unroll
      for (int m = 0; m < 4; ++m) {
        #pragma unroll
        for (int r = 0; r < 4; ++r) {
          const long idx = (orow + m * 16 + r) * (long)N + cc;
          O[idx] = acc[m][n][r] + bv + resid[idx];
        }
      }
    }
  } else if constexpr (MODE == 5) {
    bf16* O = (bf16*)out + (long)bz * sOb;
    #pragma unroll
    for (int m = 0; m < 4; ++m) {
      #pragma unroll
      for (int r = 0; r < 4; ++r) {
        const long rr = orow + m * 16 + r;
        const float inv = 1.0f / rsum[bz * rsS + rr];
        #pragma unroll
        for (int n = 0; n < 4; ++n)
          O[rr * (long)N + ocol + n * 16] = __float2bfloat16(acc[m][n][r] * inv);
      }
    }
  } else {  // MODE 6: p = exp(acc*scale), accumulate row sums
    bf16* O = (bf16*)out + (long)bz * sOb;
    #pragma unroll
    for (int m = 0; m < 4; ++m) {
      #pragma unroll
      for (int r = 0; r < 4; ++r) {
        const long rr = orow + m * 16 + r;
        float prow = 0.f;
        #pragma unroll
        for (int n = 0; n < 4; ++n) {
          const float p = __expf(acc[m][n][r] * scale);
          O[rr * (long)N + ocol + n * 16] = __float2bfloat16(p);
          prow += p;
        }
        // sum across the 16 lanes sharing these rows (same g, t=0..15)
        prow += __shfl_xor(prow, 1);
        prow += __shfl_xor(prow, 2);
        prow += __shfl_xor(prow, 4);
        prow += __shfl_xor(prow, 8);
        if (t == 0) atomicAdd(&rsum[bz * rsS + rr], prow);
      }
    }
  }
}

// row LayerNorm over D=768, fp32 in -> bf16 out
__global__ __launch_bounds__(256)
void ln_kernel(const float* __restrict__ X, const float* __restrict__ G,
               const float* __restrict__ Bv, bf16* __restrict__ H)
{
  const int tid = threadIdx.x;
  const long row = blockIdx.x;
  const float* xr = X + row * 768;
  const float v0 = xr[tid], v1 = xr[tid + 256], v2 = xr[tid + 512];
  float s = v0 + v1 + v2;
  float s2 = v0 * v0 + v1 * v1 + v2 * v2;
  #pragma unroll
  for (int o = 32; o > 0; o >>= 1) {
    s += __shfl_xor(s, o);
    s2 += __shfl_xor(s2, o);
  }
  __shared__ float red[8];
  const int w = tid >> 6, l = tid & 63;
  if (l == 0) { red[w] = s; red[w + 4] = s2; }
  __syncthreads();
  s = red[0] + red[1] + red[2] + red[3];
  s2 = red[4] + red[5] + red[6] + red[7];
  const float mu = s * (1.f / 768.f);
  const float var = s2 * (1.f / 768.f) - mu * mu;
  const float rstd = rsqrtf(var + 1e-5f);
  bf16* hr = H + row * 768;
  hr[tid]       = __float2bfloat16((v0 - mu) * rstd * G[tid]       + Bv[tid]);
  hr[tid + 256] = __float2bfloat16((v1 - mu) * rstd * G[tid + 256] + Bv[tid + 256]);
  hr[tid + 512] = __float2bfloat16((v2 - mu) * rstd * G[tid + 512] + Bv[tid + 512]);
}

// Wt[n][k] = bf16(W[k][n]) ; W fp32 [K][N]. block (32,8)
__global__ void transpose_w(const float* __restrict__ W, bf16* __restrict__ Wt,
                            int K, int N)
{
  __shared__ float tile[32][33];
  const int n0 = blockIdx.x * 32, k0 = blockIdx.y * 32;
  const int tx = threadIdx.x, ty = threadIdx.y;
  #pragma unroll
  for (int j = ty; j < 32; j += 8)
    tile[j][tx] = W[(long)(k0 + j) * N + n0 + tx];
  __syncthreads();
  #pragma unroll
  for (int j = ty; j < 32; j += 8)
    Wt[(long)(n0 + j) * K + k0 + tx] = __float2bfloat16(tile[tx][j]);
}

// Vt[b][d][s] = qkv[(b*2048+s)*2304 + 1536 + d]  (bf16 v-slice of fused qkv)
__global__ void transpose_v(const bf16* __restrict__ QKV, bf16* __restrict__ Vt)
{
  __shared__ bf16 tile[32][33];
  const int d0 = blockIdx.x * 32, s0 = blockIdx.y * 32, b = blockIdx.z;
  const int tx = threadIdx.x, ty = threadIdx.y;
  #pragma unroll
  for (int j = ty; j < 32; j += 8)
    tile[j][tx] = QKV[((long)b * 2048 + s0 + j) * 2304 + 1536 + d0 + tx];
  __syncthreads();
  #pragma unroll
  for (int j = ty; j < 32; j += 8)
    Vt[(long)b * 768 * 2048 + (long)(d0 + j) * 2048 + s0 + tx] = tile[tx][j];
}

// concat 3x768 fp32 biases
__global__ void concat3(const float* __restrict__ a, const float* __restrict__ b,
                        const float* __restrict__ c, float* __restrict__ o)
{
  const int i = threadIdx.x + blockIdx.x * 256;
  if (i < 768) { o[i] = a[i]; o[i + 768] = b[i]; o[i + 1536] = c[i]; }
}

__global__ void zerof(float* __restrict__ p, int n)
{
  const int i = threadIdx.x + blockIdx.x * 256;
  if (i < n) p[i] = 0.f;
}

extern "C" void kernel_launch(void* const* d_in, const int* in_sizes, int n_in,
                              void* d_out, int out_size, void* d_ws, size_t ws_size,
                              hipStream_t stream)
{
  const float* x     = (const float*)d_in[0];
  const float* ln1g  = (const float*)d_in[1];
  const float* ln1b  = (const float*)d_in[2];
  const float* ln2g  = (const float*)d_in[3];
  const float* ln2b  = (const float*)d_in[4];
  const float* Wq    = (const float*)d_in[5];
  const float* bq    = (const float*)d_in[6];
  const float* Wk    = (const float*)d_in[7];
  const float* bk    = (const float*)d_in[8];
  const float* Wv    = (const float*)d_in[9];
  const float* bvv   = (const float*)d_in[10];
  const float* Wo    = (const float*)d_in[11];
  const float* bo    = (const float*)d_in[12];
  const float* Wfc   = (const float*)d_in[13];
  const float* bfc   = (const float*)d_in[14];
  const float* Wproj = (const float*)d_in[15];
  const float* bproj = (const float*)d_in[16];
  float* out = (float*)d_out;

  constexpr int Bz = 8, S = 2048, D = 768, Hh = 3072, QKVN = 3 * D;
  constexpr long Mtot = (long)Bz * S;  // 16384

  char* ws = (char*)d_ws;
  size_t off = 0;
  auto alloc = [&](size_t bytes) -> char* {
    char* p = ws + off;
    off += (bytes + 255) & ~(size_t)255;
    return p;
  };
  bf16* wqkvT = (bf16*)alloc((size_t)QKVN * D * 2);
  bf16* woT   = (bf16*)alloc((size_t)D * D * 2);
  bf16* wfcT  = (bf16*)alloc((size_t)Hh * D * 2);
  bf16* wprT  = (bf16*)alloc((size_t)D * Hh * 2);
  float* bqkv = (float*)alloc((size_t)QKVN * 4);
  float* rsum = (float*)alloc((size_t)Mtot * 4);
  bf16* hb    = (bf16*)alloc((size_t)Mtot * D * 2);
  bf16* qkv   = (bf16*)alloc((size_t)Mtot * QKVN * 2);
  bf16* vtb   = (bf16*)alloc((size_t)Mtot * D * 2);
  bf16* yb    = (bf16*)alloc((size_t)Mtot * D * 2);

  int nbat = Bz;
  size_t region = (size_t)nbat * S * S * 2;              // p (bf16 probs)
  const size_t mbytes = (size_t)Mtot * Hh * 2;           // MLP hidden bf16
  if (region < mbytes) region = mbytes;
  if (off + region > ws_size) {                          // fallback: per-batch
    nbat = 1;
    region = mbytes;
  }
  char* reg = alloc(region);
  bf16* attn = (bf16*)reg;
  bf16* mb = (bf16*)reg;  // aliases attn (used after attention done)

  const dim3 tb(32, 8);

  // weight prep (bf16, [N][K]); q/k/v stacked into wqkvT rows 0/768/1536
  transpose_w<<<dim3(D / 32, D / 32), tb, 0, stream>>>(Wq, wqkvT, D, D);
  transpose_w<<<dim3(D / 32, D / 32), tb, 0, stream>>>(Wk, wqkvT + (size_t)D * D, D, D);
  transpose_w<<<dim3(D / 32, D / 32), tb, 0, stream>>>(Wv, wqkvT + 2 * (size_t)D * D, D, D);
  transpose_w<<<dim3(D / 32, D / 32), tb, 0, stream>>>(Wo, woT, D, D);
  transpose_w<<<dim3(Hh / 32, D / 32), tb, 0, stream>>>(Wfc, wfcT, D, Hh);
  transpose_w<<<dim3(D / 32, Hh / 32), tb, 0, stream>>>(Wproj, wprT, Hh, D);
  concat3<<<3, 256, 0, stream>>>(bq, bk, bvv, bqkv);
  zerof<<<(int)(Mtot / 256), 256, 0, stream>>>(rsum, (int)Mtot);

  // LN1 -> h (bf16)
  ln_kernel<<<(int)Mtot, 256, 0, stream>>>(x, ln1g, ln1b, hb);

  // fused QKV projection: [16384,768] @ [2304,768]^T -> [16384,2304]
  gemm_bt<0><<<dim3(Mtot / 128, QKVN / 128, 1), 256, 0, stream>>>(
      hb, 0, D, wqkvT, 0, D, bqkv, nullptr, nullptr, 0, qkv, 0, QKVN, D, 1.f);
  transpose_v<<<dim3(D / 32, S / 32, Bz), tb, 0, stream>>>(qkv, vtb);

  // attention: p = exp(QK^T*sc) with fused row-sums, then PV with division
  const float sc = 0.03608439182435161f;  // 1/sqrt(768)
  for (int g0 = 0; g0 < Bz; g0 += nbat) {
    const bf16* qg  = qkv + (long)g0 * S * QKVN;          // q slice, lda=2304
    const bf16* kg  = qkv + (long)g0 * S * QKVN + D;      // k slice, ldb=2304
    const bf16* vtg = vtb + (long)g0 * D * S;
    float* rsg = rsum + (long)g0 * S;
    bf16* yg = yb + (long)g0 * S * D;
    gemm_bt<6><<<dim3(S / 128, S / 128, nbat), 256, 0, stream>>>(
        qg, (long)S * QKVN, QKVN, kg, (long)S * QKVN, QKVN, nullptr, nullptr,
        rsg, S, attn, (long)S * S, S, D, sc);
    gemm_bt<5><<<dim3(S / 128, D / 128, nbat), 256, 0, stream>>>(
        attn, (long)S * S, S, vtg, (long)D * S, S, nullptr, nullptr,
        rsg, S, yg, (long)S * D, D, S, 1.f);
  }

  // out-projection + residual -> d_out (fp32)
  gemm_bt<3><<<dim3(Mtot / 128, D / 128, 1), 256, 0, stream>>>(
      yb, 0, D, woT, 0, D, bo, x, nullptr, 0, out, 0, D, D, 1.f);

  // LN2 -> h2 (bf16, reuse hb)
  ln_kernel<<<(int)Mtot, 256, 0, stream>>>(out, ln2g, ln2b, hb);

  // MLP: fc + exact GELU -> mb (bf16), then proj + residual (in-place on d_out)
  gemm_bt<4><<<dim3(Mtot / 128, Hh / 128, 1), 256, 0, stream>>>(
      hb, 0, D, wfcT, 0, D, bfc, nullptr, nullptr, 0, mb, 0, Hh, D, 1.f);
  gemm_bt<3><<<dim3(Mtot / 128, D / 128, 1), 256, 0, stream>>>(
      mb, 0, Hh, wprT, 0, Hh, bproj, out, nullptr, 0, out, 0, D, Hh, 1.f);
}

// Round 7
// 665.037 us; speedup vs baseline: 2.3253x; 1.0397x over previous
//
#include <hip/hip_runtime.h>
#include <hip/hip_bf16.h>

typedef __attribute__((ext_vector_type(8))) short short8;
typedef __attribute__((ext_vector_type(4))) float floatx4;

using bf16 = __hip_bfloat16;

__device__ __forceinline__ void cp16_g2l(bf16* lds_p, const bf16* g) {
  __builtin_amdgcn_global_load_lds(
      (const __attribute__((address_space(1))) unsigned int*)g,
      (__attribute__((address_space(3))) unsigned int*)lds_p,
      16, 0, 0);
}

__device__ __forceinline__ float gelu_exact(float x) {
  return 0.5f * x * (1.0f + erff(x * 0.70710678118654752f));
}

// ---------------------------------------------------------------------------
// 128x128 tile GEMM, BK=32, 4 waves, mfma_f32_16x16x32_bf16 (r5 engine).
// C[M,N] = A[M,K] @ Bt[N,K]^T, batched via blockIdx.z.
// T2 swizzle (rule #21): 16B slot u of row r at physical u^((r>>1)&3);
// lane-linear gload_lds dest, inverse-swizzled global SOURCE, XORed ds_read.
//
// Panel-16 layout (for P): elem(row,col) at (col>>4)*(PR*16) + row*16 +
// (col&15), PR = panel row count. Writes become row-contiguous 2B streams
// (sector-dense) instead of 2B scatters at 4KB row stride.
//   MODE 6 (scores): OUT in panels (PR = rsS); row-sum partials to
//     rsum[(blockIdx.y*2 + wc)*cbStr + bz*rsS + row]  -- WAVE-UNIQUE slot
//     (r6 bug: slot lacked wc; the two wc-waves of a block share rows and
//      raced on plain stores, halving the softmax denominator).
//   MODE 5 (PV):     A-operand READ from panels (PR = lda).
// MODE 0: out bf16 = acc + bias
// MODE 3: out f32  = acc + bias + resid (resid may alias out)
// MODE 4: out bf16 = gelu(acc + bias)
// MODE 5: out bf16 = acc / rsum[bz*rsS + row]   (A from panel-16)
// MODE 6: out bf16 = exp(acc*scale) to panel-16, partial row-sums to rsum
// ---------------------------------------------------------------------------
template<int MODE>
__global__ __launch_bounds__(256)
void gemm_bt(const bf16* __restrict__ A, long sAb, long lda,
             const bf16* __restrict__ Bt, long sBb, long ldb,
             const float* __restrict__ bias,
             const float* __restrict__ resid,
             float* __restrict__ rsum, long rsS, long cbStr,
             void* __restrict__ out, long sOb,
             int N, int K, float scale)
{
  constexpr bool PA = (MODE == 5);   // A operand lives in panel-16 layout

  __shared__ __attribute__((aligned(16))) bf16 sA[2][128 * 32];
  __shared__ __attribute__((aligned(16))) bf16 sB[2][128 * 32];

  const int tid = threadIdx.x;
  const int l = tid & 63, w = tid >> 6;
  const int bz = blockIdx.z;
  const long row0 = (long)blockIdx.x * 128;
  const long col0 = (long)blockIdx.y * 128;

  const bf16* Ab = A + (long)bz * sAb;
  const bf16* Bb = Bt + (long)bz * sBb;

  // staging: wave w covers rows [w*16,+16) and [+64); 4x 16B slots per row
  const int sr = (w << 4) + (l >> 2);                  // 0..63
  const int slot = (l & 3) ^ ((sr >> 1) & 3);          // inverse-swizzled src
  const int kcd = (l & 3) << 3;                        // lane-linear dest
  const bf16* gA;
  long skipA, koA;
  if constexpr (PA) {
    gA    = Ab + ((long)(slot >> 1) * lda + row0 + sr) * 16 + ((slot & 1) << 3);
    skipA = 64 * 16;          // +64 rows within a panel
    koA   = 32 * lda;         // per-K-step advance (2 panels)
  } else {
    gA    = Ab + (row0 + sr) * lda + (slot << 3);
    skipA = 64 * lda;
    koA   = 32;
  }
  const bf16* gB = Bb + (col0 + sr) * ldb + (slot << 3);
  const long skipB = 64 * ldb;
  bf16* lA = &sA[0][sr * 32 + kcd];
  bf16* lB = &sB[0][sr * 32 + kcd];

  floatx4 acc[4][4];
  #pragma unroll
  for (int i = 0; i < 4; ++i)
    #pragma unroll
    for (int j = 0; j < 4; ++j)
      acc[i][j] = (floatx4){0.f, 0.f, 0.f, 0.f};

  const int wr = (w >> 1) & 1, wc = w & 1;
  const int g = l >> 4, t = l & 15;
  const int swz = (g ^ ((t >> 1) & 3)) << 3;           // swizzled ds_read slot
  const int aoff = (wr * 64 + t) * 32 + swz;
  const int boff = (wc * 64 + t) * 32 + swz;

  const int nt = K >> 5;

  // prologue: stage tile 0 into buf 0
  cp16_g2l(lA,           gA);
  cp16_g2l(lA + 64 * 32, gA + skipA);
  cp16_g2l(lB,           gB);
  cp16_g2l(lB + 64 * 32, gB + skipB);
  __syncthreads();   // drains vmcnt(0)

  for (int kt = 0; kt < nt; ++kt) {
    const int cur = kt & 1;
    if (kt + 1 < nt) {
      const long oA = (long)(kt + 1) * koA;
      const long oB = (long)(kt + 1) << 5;
      bf16* dA = lA + (cur ^ 1) * (128 * 32);
      bf16* dB = lB + (cur ^ 1) * (128 * 32);
      cp16_g2l(dA,           gA + oA);
      cp16_g2l(dA + 64 * 32, gA + oA + skipA);
      cp16_g2l(dB,           gB + oB);
      cp16_g2l(dB + 64 * 32, gB + oB + skipB);
    }
    const bf16* cA = &sA[cur][0];
    const bf16* cB = &sB[cur][0];
    short8 a[4], b[4];
    #pragma unroll
    for (int m = 0; m < 4; ++m) a[m] = *(const short8*)(cA + aoff + m * 512);
    #pragma unroll
    for (int n = 0; n < 4; ++n) b[n] = *(const short8*)(cB + boff + n * 512);
    #pragma unroll
    for (int m = 0; m < 4; ++m)
      #pragma unroll
      for (int n = 0; n < 4; ++n)
        acc[m][n] = __builtin_amdgcn_mfma_f32_16x16x32_bf16(a[m], b[n], acc[m][n], 0, 0, 0);
    __syncthreads();   // drains this iter's prefetch + everyone's ds_reads
  }

  // epilogue: C/D layout col = lane&15, row = (lane>>4)*4 + r  [m89]
  const long orow = row0 + wr * 64 + (g << 2);
  const long ocol = col0 + wc * 64 + t;

  if constexpr (MODE == 0 || MODE == 4) {
    bf16* O = (bf16*)out + (long)bz * sOb;
    float bv4[4];
    #pragma unroll
    for (int n = 0; n < 4; ++n) bv4[n] = bias[ocol + n * 16];
    #pragma unroll
    for (int m = 0; m < 4; ++m) {
      #pragma unroll
      for (int r = 0; r < 4; ++r) {
        bf16* Or = O + (orow + m * 16 + r) * (long)N + ocol;
        #pragma unroll
        for (int n = 0; n < 4; ++n) {      // n innermost: row-dense stores
          float vv = acc[m][n][r] + bv4[n];
          if constexpr (MODE == 4) vv = gelu_exact(vv);
          Or[n * 16] = __float2bfloat16(vv);
        }
      }
    }
  } else if constexpr (MODE == 3) {
    float* O = (float*)out;
    float bv4[4];
    #pragma unroll
    for (int n = 0; n < 4; ++n) bv4[n] = bias[ocol + n * 16];
    #pragma unroll
    for (int m = 0; m < 4; ++m) {
      #pragma unroll
      for (int r = 0; r < 4; ++r) {
        const long rb = (orow + m * 16 + r) * (long)N + ocol;
        #pragma unroll
        for (int n = 0; n < 4; ++n)
          O[rb + n * 16] = acc[m][n][r] + bv4[n] + resid[rb + n * 16];
      }
    }
  } else if constexpr (MODE == 5) {
    bf16* O = (bf16*)out + (long)bz * sOb;
    #pragma unroll
    for (int m = 0; m < 4; ++m) {
      #pragma unroll
      for (int r = 0; r < 4; ++r) {
        const long rr = orow + m * 16 + r;
        const float inv = 1.0f / rsum[bz * rsS + rr];
        bf16* Or = O + rr * (long)N + ocol;
        #pragma unroll
        for (int n = 0; n < 4; ++n)
          Or[n * 16] = __float2bfloat16(acc[m][n][r] * inv);
      }
    }
  } else {  // MODE 6: panel-16 exp output + wave-unique partial row sums
    bf16* O = (bf16*)out + (long)bz * sOb;
    const long pb = (col0 >> 4) + wc * 4;              // panel index base
    float prow[4][4];
    #pragma unroll
    for (int m = 0; m < 4; ++m)
      #pragma unroll
      for (int r = 0; r < 4; ++r) prow[m][r] = 0.f;
    #pragma unroll
    for (int n = 0; n < 4; ++n) {                      // n outer: panel-dense
      bf16* Opan = O + (pb + n) * (rsS * 16) + t;
      #pragma unroll
      for (int m = 0; m < 4; ++m) {
        #pragma unroll
        for (int r = 0; r < 4; ++r) {
          const float p = __expf(acc[m][n][r] * scale);
          Opan[(orow + m * 16 + r) * 16] = __float2bfloat16(p);
          prow[m][r] += p;
        }
      }
    }
    #pragma unroll
    for (int m = 0; m < 4; ++m) {
      #pragma unroll
      for (int r = 0; r < 4; ++r) {
        float s = prow[m][r];
        s += __shfl_xor(s, 1);
        s += __shfl_xor(s, 2);
        s += __shfl_xor(s, 4);
        s += __shfl_xor(s, 8);
        if (t == 0)
          rsum[(long)(blockIdx.y * 2 + wc) * cbStr + bz * rsS +
               orow + m * 16 + r] = s;                 // wave-unique slot
      }
    }
  }
}

// rsum[i] = sum over 32 column-block partials (64 cols each)
__global__ __launch_bounds__(256)
void reduce32(const float* __restrict__ rp, float* __restrict__ rs, int n)
{
  const int i = threadIdx.x + blockIdx.x * 256;
  if (i < n) {
    float s = 0.f;
    #pragma unroll
    for (int c = 0; c < 32; ++c) s += rp[(long)c * 16384 + i];
    rs[i] = s;
  }
}

// row LayerNorm over D=768, fp32 in -> bf16 out
__global__ __launch_bounds__(256)
void ln_kernel(const float* __restrict__ X, const float* __restrict__ G,
               const float* __restrict__ Bv, bf16* __restrict__ H)
{
  const int tid = threadIdx.x;
  const long row = blockIdx.x;
  const float* xr = X + row * 768;
  const float v0 = xr[tid], v1 = xr[tid + 256], v2 = xr[tid + 512];
  float s = v0 + v1 + v2;
  float s2 = v0 * v0 + v1 * v1 + v2 * v2;
  #pragma unroll
  for (int o = 32; o > 0; o >>= 1) {
    s += __shfl_xor(s, o);
    s2 += __shfl_xor(s2, o);
  }
  __shared__ float red[8];
  const int w = tid >> 6, l = tid & 63;
  if (l == 0) { red[w] = s; red[w + 4] = s2; }
  __syncthreads();
  s = red[0] + red[1] + red[2] + red[3];
  s2 = red[4] + red[5] + red[6] + red[7];
  const float mu = s * (1.f / 768.f);
  const float var = s2 * (1.f / 768.f) - mu * mu;
  const float rstd = rsqrtf(var + 1e-5f);
  bf16* hr = H + row * 768;
  hr[tid]       = __float2bfloat16((v0 - mu) * rstd * G[tid]       + Bv[tid]);
  hr[tid + 256] = __float2bfloat16((v1 - mu) * rstd * G[tid + 256] + Bv[tid + 256]);
  hr[tid + 512] = __float2bfloat16((v2 - mu) * rstd * G[tid + 512] + Bv[tid + 512]);
}

// Wt[n][k] = bf16(W[k][n]) ; W fp32 [K][N]. block (32,8)
__global__ void transpose_w(const float* __restrict__ W, bf16* __restrict__ Wt,
                            int K, int N)
{
  __shared__ float tile[32][33];
  const int n0 = blockIdx.x * 32, k0 = blockIdx.y * 32;
  const int tx = threadIdx.x, ty = threadIdx.y;
  #pragma unroll
  for (int j = ty; j < 32; j += 8)
    tile[j][tx] = W[(long)(k0 + j) * N + n0 + tx];
  __syncthreads();
  #pragma unroll
  for (int j = ty; j < 32; j += 8)
    Wt[(long)(n0 + j) * K + k0 + tx] = __float2bfloat16(tile[tx][j]);
}

// Vt[b][d][s] = qkv[(b*2048+s)*2304 + 1536 + d]  (bf16 v-slice of fused qkv)
__global__ void transpose_v(const bf16* __restrict__ QKV, bf16* __restrict__ Vt)
{
  __shared__ bf16 tile[32][33];
  const int d0 = blockIdx.x * 32, s0 = blockIdx.y * 32, b = blockIdx.z;
  const int tx = threadIdx.x, ty = threadIdx.y;
  #pragma unroll
  for (int j = ty; j < 32; j += 8)
    tile[j][tx] = QKV[((long)b * 2048 + s0 + j) * 2304 + 1536 + d0 + tx];
  __syncthreads();
  #pragma unroll
  for (int j = ty; j < 32; j += 8)
    Vt[(long)b * 768 * 2048 + (long)(d0 + j) * 2048 + s0 + tx] = tile[tx][j];
}

// concat 3x768 fp32 biases
__global__ void concat3(const float* __restrict__ a, const float* __restrict__ b,
                        const float* __restrict__ c, float* __restrict__ o)
{
  const int i = threadIdx.x + blockIdx.x * 256;
  if (i < 768) { o[i] = a[i]; o[i + 768] = b[i]; o[i + 1536] = c[i]; }
}

extern "C" void kernel_launch(void* const* d_in, const int* in_sizes, int n_in,
                              void* d_out, int out_size, void* d_ws, size_t ws_size,
                              hipStream_t stream)
{
  const float* x     = (const float*)d_in[0];
  const float* ln1g  = (const float*)d_in[1];
  const float* ln1b  = (const float*)d_in[2];
  const float* ln2g  = (const float*)d_in[3];
  const float* ln2b  = (const float*)d_in[4];
  const float* Wq    = (const float*)d_in[5];
  const float* bq    = (const float*)d_in[6];
  const float* Wk    = (const float*)d_in[7];
  const float* bk    = (const float*)d_in[8];
  const float* Wv    = (const float*)d_in[9];
  const float* bvv   = (const float*)d_in[10];
  const float* Wo    = (const float*)d_in[11];
  const float* bo    = (const float*)d_in[12];
  const float* Wfc   = (const float*)d_in[13];
  const float* bfc   = (const float*)d_in[14];
  const float* Wproj = (const float*)d_in[15];
  const float* bproj = (const float*)d_in[16];
  float* out = (float*)d_out;

  constexpr int Bz = 8, S = 2048, D = 768, Hh = 3072, QKVN = 3 * D;
  constexpr long Mtot = (long)Bz * S;  // 16384

  char* ws = (char*)d_ws;
  size_t off = 0;
  auto alloc = [&](size_t bytes) -> char* {
    char* p = ws + off;
    off += (bytes + 255) & ~(size_t)255;
    return p;
  };
  bf16* wqkvT = (bf16*)alloc((size_t)QKVN * D * 2);
  bf16* woT   = (bf16*)alloc((size_t)D * D * 2);
  bf16* wfcT  = (bf16*)alloc((size_t)Hh * D * 2);
  bf16* wprT  = (bf16*)alloc((size_t)D * Hh * 2);
  float* bqkv = (float*)alloc((size_t)QKVN * 4);
  float* rsum = (float*)alloc((size_t)Mtot * 4);
  float* rpart= (float*)alloc((size_t)32 * Mtot * 4);   // [colblk64][Mtot]
  bf16* hb    = (bf16*)alloc((size_t)Mtot * D * 2);
  bf16* qkv   = (bf16*)alloc((size_t)Mtot * QKVN * 2);
  bf16* vtb   = (bf16*)alloc((size_t)Mtot * D * 2);
  bf16* yb    = (bf16*)alloc((size_t)Mtot * D * 2);

  int nbat = Bz;
  size_t region = (size_t)nbat * S * S * 2;              // p (bf16, panel-16)
  const size_t mbytes = (size_t)Mtot * Hh * 2;           // MLP hidden bf16
  if (region < mbytes) region = mbytes;
  if (off + region > ws_size) {                          // fallback: per-batch
    nbat = 1;
    region = mbytes;
  }
  char* reg = alloc(region);
  bf16* attn = (bf16*)reg;
  bf16* mb = (bf16*)reg;  // aliases attn (used after attention done)

  const dim3 tb(32, 8);

  // weight prep (bf16, [N][K]); q/k/v stacked into wqkvT rows 0/768/1536
  transpose_w<<<dim3(D / 32, D / 32), tb, 0, stream>>>(Wq, wqkvT, D, D);
  transpose_w<<<dim3(D / 32, D / 32), tb, 0, stream>>>(Wk, wqkvT + (size_t)D * D, D, D);
  transpose_w<<<dim3(D / 32, D / 32), tb, 0, stream>>>(Wv, wqkvT + 2 * (size_t)D * D, D, D);
  transpose_w<<<dim3(D / 32, D / 32), tb, 0, stream>>>(Wo, woT, D, D);
  transpose_w<<<dim3(Hh / 32, D / 32), tb, 0, stream>>>(Wfc, wfcT, D, Hh);
  transpose_w<<<dim3(D / 32, Hh / 32), tb, 0, stream>>>(Wproj, wprT, Hh, D);
  concat3<<<3, 256, 0, stream>>>(bq, bk, bvv, bqkv);

  // LN1 -> h (bf16)
  ln_kernel<<<(int)Mtot, 256, 0, stream>>>(x, ln1g, ln1b, hb);

  // fused QKV projection: [16384,768] @ [2304,768]^T -> [16384,2304]
  gemm_bt<0><<<dim3(Mtot / 128, QKVN / 128, 1), 256, 0, stream>>>(
      hb, 0, D, wqkvT, 0, D, bqkv, nullptr, nullptr, 0, 0, qkv, 0, QKVN, D, 1.f);
  transpose_v<<<dim3(D / 32, S / 32, Bz), tb, 0, stream>>>(qkv, vtb);

  // attention: p = exp(QK^T*sc) (panel-16, partial sums) -> reduce -> PV/div
  const float sc = 0.03608439182435161f;  // 1/sqrt(768)
  for (int g0 = 0; g0 < Bz; g0 += nbat) {
    const bf16* qg  = qkv + (long)g0 * S * QKVN;          // q slice, lda=2304
    const bf16* kg  = qkv + (long)g0 * S * QKVN + D;      // k slice, ldb=2304
    const bf16* vtg = vtb + (long)g0 * D * S;
    float* rsg = rsum + (long)g0 * S;
    float* rpg = rpart + (long)g0 * S;
    bf16* yg = yb + (long)g0 * S * D;
    gemm_bt<6><<<dim3(S / 128, S / 128, nbat), 256, 0, stream>>>(
        qg, (long)S * QKVN, QKVN, kg, (long)S * QKVN, QKVN, nullptr, nullptr,
        rpg, S, Mtot, attn, (long)S * S, S, D, sc);
    reduce32<<<(int)(Mtot / 256), 256, 0, stream>>>(rpart, rsum, (int)Mtot);
    gemm_bt<5><<<dim3(S / 128, D / 128, nbat), 256, 0, stream>>>(
        attn, (long)S * S, S, vtg, (long)D * S, S, nullptr, nullptr,
        rsg, S, 0, yg, (long)S * D, D, S, 1.f);
  }

  // out-projection + residual -> d_out (fp32)
  gemm_bt<3><<<dim3(Mtot / 128, D / 128, 1), 256, 0, stream>>>(
      yb, 0, D, woT, 0, D, bo, x, nullptr, 0, 0, out, 0, D, D, 1.f);

  // LN2 -> h2 (bf16, reuse hb)
  ln_kernel<<<(int)Mtot, 256, 0, stream>>>(out, ln2g, ln2b, hb);

  // MLP: fc + exact GELU -> mb (bf16), then proj + residual (in-place on d_out)
  gemm_bt<4><<<dim3(Mtot / 128, Hh / 128, 1), 256, 0, stream>>>(
      hb, 0, D, wfcT, 0, D, bfc, nullptr, nullptr, 0, 0, mb, 0, Hh, D, 1.f);
  gemm_bt<3><<<dim3(Mtot / 128, D / 128, 1), 256, 0, stream>>>(
      mb, 0, Hh, wprT, 0, Hh, bproj, out, nullptr, 0, 0, out, 0, D, Hh, 1.f);
}

// Round 8
// 625.645 us; speedup vs baseline: 2.4717x; 1.0630x over previous
//
#include <hip/hip_runtime.h>
#include <hip/hip_bf16.h>

typedef __attribute__((ext_vector_type(8))) short short8;
typedef __attribute__((ext_vector_type(4))) float floatx4;

using bf16 = __hip_bfloat16;

__device__ __forceinline__ void cp16_g2l(bf16* lds_p, const bf16* g) {
  __builtin_amdgcn_global_load_lds(
      (const __attribute__((address_space(1))) unsigned int*)g,
      (__attribute__((address_space(3))) unsigned int*)lds_p,
      16, 0, 0);
}

__device__ __forceinline__ float gelu_exact(float x) {
  return 0.5f * x * (1.0f + erff(x * 0.70710678118654752f));
}

// ---------------------------------------------------------------------------
// 128x128 tile GEMM, BK=32, 4 waves, mfma_f32_16x16x32_bf16.
// r8 change (T4): 3-deep LDS ring (48 KiB, keeps 3 blocks/CU) + ONE raw
// s_barrier per K-step + counted vmcnt(4) that never drains mid-loop.
//   iter t: stage(t+1 -> buf (t+1)%3); vmcnt(4); s_barrier; ds_read(t); MFMA.
//   Ledger (4 loads/thread/step): after issue 8 outstanding; vmcnt(4) ==
//   tile t landed, t+1 in flight. Race check: reads of t-1 are in epoch
//   (b_{t-1}, b_t); buf (t+1)%3 differs from bufs t%3,(t-1)%3 and its old
//   tile t-2 was sealed by b_{t-1}. Ring-2 would race; ring-3 is sound.
// T2 swizzle (rule #21): 16B slot u of row r at physical u^((r>>1)&3);
// lane-linear gload_lds dest, inverse-swizzled global SOURCE, XORed ds_read.
// Panel-16 layout for P (r7): elem(row,col) at (col>>4)*(PR*16)+row*16+
// (col&15). MODE 6 writes it (sector-dense); MODE 5 stages A from it.
// MODE 0: out bf16 = acc + bias
// MODE 3: out f32  = acc + bias + resid (resid may alias out)
// MODE 4: out bf16 = gelu(acc + bias)
// MODE 5: out bf16 = acc / rsum[bz*rsS + row]   (A from panel-16)
// MODE 6: out bf16 = exp(acc*scale) to panel-16; wave-unique row-sum
//         partials to rsum[(blockIdx.y*2+wc)*cbStr + bz*rsS + row]
// ---------------------------------------------------------------------------
template<int MODE>
__global__ __launch_bounds__(256)
void gemm_bt(const bf16* __restrict__ A, long sAb, long lda,
             const bf16* __restrict__ Bt, long sBb, long ldb,
             const float* __restrict__ bias,
             const float* __restrict__ resid,
             float* __restrict__ rsum, long rsS, long cbStr,
             void* __restrict__ out, long sOb,
             int N, int K, float scale)
{
  constexpr bool PA = (MODE == 5);   // A operand lives in panel-16 layout

  __shared__ __attribute__((aligned(16))) bf16 sA[3][128 * 32];
  __shared__ __attribute__((aligned(16))) bf16 sB[3][128 * 32];

  const int tid = threadIdx.x;
  const int l = tid & 63, w = tid >> 6;
  const int bz = blockIdx.z;
  const long row0 = (long)blockIdx.x * 128;
  const long col0 = (long)blockIdx.y * 128;

  const bf16* Ab = A + (long)bz * sAb;
  const bf16* Bb = Bt + (long)bz * sBb;

  // staging: wave w covers rows [w*16,+16) and [+64); 4x 16B slots per row
  const int sr = (w << 4) + (l >> 2);                  // 0..63
  const int slot = (l & 3) ^ ((sr >> 1) & 3);          // inverse-swizzled src
  const int kcd = (l & 3) << 3;                        // lane-linear dest
  const bf16* gA;
  long skipA, koA;
  if constexpr (PA) {
    gA    = Ab + ((long)(slot >> 1) * lda + row0 + sr) * 16 + ((slot & 1) << 3);
    skipA = 64 * 16;          // +64 rows within a panel
    koA   = 32 * lda;         // per-K-step advance (2 panels)
  } else {
    gA    = Ab + (row0 + sr) * lda + (slot << 3);
    skipA = 64 * lda;
    koA   = 32;
  }
  const bf16* gB = Bb + (col0 + sr) * ldb + (slot << 3);
  const long skipB = 64 * ldb;
  const int lofs = sr * 32 + kcd;

  floatx4 acc[4][4];
  #pragma unroll
  for (int i = 0; i < 4; ++i)
    #pragma unroll
    for (int j = 0; j < 4; ++j)
      acc[i][j] = (floatx4){0.f, 0.f, 0.f, 0.f};

  const int wr = (w >> 1) & 1, wc = w & 1;
  const int g = l >> 4, t = l & 15;
  const int swz = (g ^ ((t >> 1) & 3)) << 3;           // swizzled ds_read slot
  const int aoff = (wr * 64 + t) * 32 + swz;
  const int boff = (wc * 64 + t) * 32 + swz;

  const int nt = K >> 5;

  // prologue: stage tile 0 into buf 0 (4 loads in flight)
  cp16_g2l(&sA[0][lofs],           gA);
  cp16_g2l(&sA[0][lofs] + 64 * 32, gA + skipA);
  cp16_g2l(&sB[0][lofs],           gB);
  cp16_g2l(&sB[0][lofs] + 64 * 32, gB + skipB);

  int bufc = 0;
  for (int kt = 0; kt < nt; ++kt) {
    const int nxtb = (bufc == 2) ? 0 : bufc + 1;
    if (kt + 1 < nt) {
      const long oA = (long)(kt + 1) * koA;
      const long oB = (long)(kt + 1) << 5;
      cp16_g2l(&sA[nxtb][lofs],           gA + oA);
      cp16_g2l(&sA[nxtb][lofs] + 64 * 32, gA + oA + skipA);
      cp16_g2l(&sB[nxtb][lofs],           gB + oB);
      cp16_g2l(&sB[nxtb][lofs] + 64 * 32, gB + oB + skipB);
      asm volatile("s_waitcnt vmcnt(4)" ::: "memory");  // tile kt landed
    } else {
      asm volatile("s_waitcnt vmcnt(0)" ::: "memory");  // final tile landed
    }
    asm volatile("s_barrier" ::: "memory");             // all waves ready

    const bf16* cA = &sA[bufc][0];
    const bf16* cB = &sB[bufc][0];
    short8 a[4], b[4];
    #pragma unroll
    for (int m = 0; m < 4; ++m) a[m] = *(const short8*)(cA + aoff + m * 512);
    #pragma unroll
    for (int n = 0; n < 4; ++n) b[n] = *(const short8*)(cB + boff + n * 512);
    #pragma unroll
    for (int m = 0; m < 4; ++m)
      #pragma unroll
      for (int n = 0; n < 4; ++n)
        acc[m][n] = __builtin_amdgcn_mfma_f32_16x16x32_bf16(a[m], b[n], acc[m][n], 0, 0, 0);
    bufc = nxtb;
  }

  // epilogue: C/D layout col = lane&15, row = (lane>>4)*4 + r  [m89]
  const long orow = row0 + wr * 64 + (g << 2);
  const long ocol = col0 + wc * 64 + t;

  if constexpr (MODE == 0 || MODE == 4) {
    bf16* O = (bf16*)out + (long)bz * sOb;
    float bv4[4];
    #pragma unroll
    for (int n = 0; n < 4; ++n) bv4[n] = bias[ocol + n * 16];
    #pragma unroll
    for (int m = 0; m < 4; ++m) {
      #pragma unroll
      for (int r = 0; r < 4; ++r) {
        bf16* Or = O + (orow + m * 16 + r) * (long)N + ocol;
        #pragma unroll
        for (int n = 0; n < 4; ++n) {      // n innermost: row-dense stores
          float vv = acc[m][n][r] + bv4[n];
          if constexpr (MODE == 4) vv = gelu_exact(vv);
          Or[n * 16] = __float2bfloat16(vv);
        }
      }
    }
  } else if constexpr (MODE == 3) {
    float* O = (float*)out;
    float bv4[4];
    #pragma unroll
    for (int n = 0; n < 4; ++n) bv4[n] = bias[ocol + n * 16];
    #pragma unroll
    for (int m = 0; m < 4; ++m) {
      #pragma unroll
      for (int r = 0; r < 4; ++r) {
        const long rb = (orow + m * 16 + r) * (long)N + ocol;
        #pragma unroll
        for (int n = 0; n < 4; ++n)
          O[rb + n * 16] = acc[m][n][r] + bv4[n] + resid[rb + n * 16];
      }
    }
  } else if constexpr (MODE == 5) {
    bf16* O = (bf16*)out + (long)bz * sOb;
    #pragma unroll
    for (int m = 0; m < 4; ++m) {
      #pragma unroll
      for (int r = 0; r < 4; ++r) {
        const long rr = orow + m * 16 + r;
        const float inv = 1.0f / rsum[bz * rsS + rr];
        bf16* Or = O + rr * (long)N + ocol;
        #pragma unroll
        for (int n = 0; n < 4; ++n)
          Or[n * 16] = __float2bfloat16(acc[m][n][r] * inv);
      }
    }
  } else {  // MODE 6: panel-16 exp output + wave-unique partial row sums
    bf16* O = (bf16*)out + (long)bz * sOb;
    const long pb = (col0 >> 4) + wc * 4;              // panel index base
    float prow[4][4];
    #pragma unroll
    for (int m = 0; m < 4; ++m)
      #pragma unroll
      for (int r = 0; r < 4; ++r) prow[m][r] = 0.f;
    #pragma unroll
    for (int n = 0; n < 4; ++n) {                      // n outer: panel-dense
      bf16* Opan = O + (pb + n) * (rsS * 16) + t;
      #pragma unroll
      for (int m = 0; m < 4; ++m) {
        #pragma unroll
        for (int r = 0; r < 4; ++r) {
          const float p = __expf(acc[m][n][r] * scale);
          Opan[(orow + m * 16 + r) * 16] = __float2bfloat16(p);
          prow[m][r] += p;
        }
      }
    }
    #pragma unroll
    for (int m = 0; m < 4; ++m) {
      #pragma unroll
      for (int r = 0; r < 4; ++r) {
        float s = prow[m][r];
        s += __shfl_xor(s, 1);
        s += __shfl_xor(s, 2);
        s += __shfl_xor(s, 4);
        s += __shfl_xor(s, 8);
        if (t == 0)
          rsum[(long)(blockIdx.y * 2 + wc) * cbStr + bz * rsS +
               orow + m * 16 + r] = s;                 // wave-unique slot
      }
    }
  }
}

// rsum[i] = sum over 32 column-block partials (64 cols each)
__global__ __launch_bounds__(256)
void reduce32(const float* __restrict__ rp, float* __restrict__ rs, int n)
{
  const int i = threadIdx.x + blockIdx.x * 256;
  if (i < n) {
    float s = 0.f;
    #pragma unroll
    for (int c = 0; c < 32; ++c) s += rp[(long)c * 16384 + i];
    rs[i] = s;
  }
}

// row LayerNorm over D=768, fp32 in -> bf16 out
__global__ __launch_bounds__(256)
void ln_kernel(const float* __restrict__ X, const float* __restrict__ G,
               const float* __restrict__ Bv, bf16* __restrict__ H)
{
  const int tid = threadIdx.x;
  const long row = blockIdx.x;
  const float* xr = X + row * 768;
  const float v0 = xr[tid], v1 = xr[tid + 256], v2 = xr[tid + 512];
  float s = v0 + v1 + v2;
  float s2 = v0 * v0 + v1 * v1 + v2 * v2;
  #pragma unroll
  for (int o = 32; o > 0; o >>= 1) {
    s += __shfl_xor(s, o);
    s2 += __shfl_xor(s2, o);
  }
  __shared__ float red[8];
  const int w = tid >> 6, l = tid & 63;
  if (l == 0) { red[w] = s; red[w + 4] = s2; }
  __syncthreads();
  s = red[0] + red[1] + red[2] + red[3];
  s2 = red[4] + red[5] + red[6] + red[7];
  const float mu = s * (1.f / 768.f);
  const float var = s2 * (1.f / 768.f) - mu * mu;
  const float rstd = rsqrtf(var + 1e-5f);
  bf16* hr = H + row * 768;
  hr[tid]       = __float2bfloat16((v0 - mu) * rstd * G[tid]       + Bv[tid]);
  hr[tid + 256] = __float2bfloat16((v1 - mu) * rstd * G[tid + 256] + Bv[tid + 256]);
  hr[tid + 512] = __float2bfloat16((v2 - mu) * rstd * G[tid + 512] + Bv[tid + 512]);
}

// Wt[n][k] = bf16(W[k][n]) ; W fp32 [K][N]. block (32,8)
__global__ void transpose_w(const float* __restrict__ W, bf16* __restrict__ Wt,
                            int K, int N)
{
  __shared__ float tile[32][33];
  const int n0 = blockIdx.x * 32, k0 = blockIdx.y * 32;
  const int tx = threadIdx.x, ty = threadIdx.y;
  #pragma unroll
  for (int j = ty; j < 32; j += 8)
    tile[j][tx] = W[(long)(k0 + j) * N + n0 + tx];
  __syncthreads();
  #pragma unroll
  for (int j = ty; j < 32; j += 8)
    Wt[(long)(n0 + j) * K + k0 + tx] = __float2bfloat16(tile[tx][j]);
}

// Vt[b][d][s] = qkv[(b*2048+s)*2304 + 1536 + d]  (bf16 v-slice of fused qkv)
__global__ void transpose_v(const bf16* __restrict__ QKV, bf16* __restrict__ Vt)
{
  __shared__ bf16 tile[32][33];
  const int d0 = blockIdx.x * 32, s0 = blockIdx.y * 32, b = blockIdx.z;
  const int tx = threadIdx.x, ty = threadIdx.y;
  #pragma unroll
  for (int j = ty; j < 32; j += 8)
    tile[j][tx] = QKV[((long)b * 2048 + s0 + j) * 2304 + 1536 + d0 + tx];
  __syncthreads();
  #pragma unroll
  for (int j = ty; j < 32; j += 8)
    Vt[(long)b * 768 * 2048 + (long)(d0 + j) * 2048 + s0 + tx] = tile[tx][j];
}

// concat 3x768 fp32 biases
__global__ void concat3(const float* __restrict__ a, const float* __restrict__ b,
                        const float* __restrict__ c, float* __restrict__ o)
{
  const int i = threadIdx.x + blockIdx.x * 256;
  if (i < 768) { o[i] = a[i]; o[i + 768] = b[i]; o[i + 1536] = c[i]; }
}

extern "C" void kernel_launch(void* const* d_in, const int* in_sizes, int n_in,
                              void* d_out, int out_size, void* d_ws, size_t ws_size,
                              hipStream_t stream)
{
  const float* x     = (const float*)d_in[0];
  const float* ln1g  = (const float*)d_in[1];
  const float* ln1b  = (const float*)d_in[2];
  const float* ln2g  = (const float*)d_in[3];
  const float* ln2b  = (const float*)d_in[4];
  const float* Wq    = (const float*)d_in[5];
  const float* bq    = (const float*)d_in[6];
  const float* Wk    = (const float*)d_in[7];
  const float* bk    = (const float*)d_in[8];
  const float* Wv    = (const float*)d_in[9];
  const float* bvv   = (const float*)d_in[10];
  const float* Wo    = (const float*)d_in[11];
  const float* bo    = (const float*)d_in[12];
  const float* Wfc   = (const float*)d_in[13];
  const float* bfc   = (const float*)d_in[14];
  const float* Wproj = (const float*)d_in[15];
  const float* bproj = (const float*)d_in[16];
  float* out = (float*)d_out;

  constexpr int Bz = 8, S = 2048, D = 768, Hh = 3072, QKVN = 3 * D;
  constexpr long Mtot = (long)Bz * S;  // 16384

  char* ws = (char*)d_ws;
  size_t off = 0;
  auto alloc = [&](size_t bytes) -> char* {
    char* p = ws + off;
    off += (bytes + 255) & ~(size_t)255;
    return p;
  };
  bf16* wqkvT = (bf16*)alloc((size_t)QKVN * D * 2);
  bf16* woT   = (bf16*)alloc((size_t)D * D * 2);
  bf16* wfcT  = (bf16*)alloc((size_t)Hh * D * 2);
  bf16* wprT  = (bf16*)alloc((size_t)D * Hh * 2);
  float* bqkv = (float*)alloc((size_t)QKVN * 4);
  float* rsum = (float*)alloc((size_t)Mtot * 4);
  float* rpart= (float*)alloc((size_t)32 * Mtot * 4);   // [colblk64][Mtot]
  bf16* hb    = (bf16*)alloc((size_t)Mtot * D * 2);
  bf16* qkv   = (bf16*)alloc((size_t)Mtot * QKVN * 2);
  bf16* vtb   = (bf16*)alloc((size_t)Mtot * D * 2);
  bf16* yb    = (bf16*)alloc((size_t)Mtot * D * 2);

  int nbat = Bz;
  size_t region = (size_t)nbat * S * S * 2;              // p (bf16, panel-16)
  const size_t mbytes = (size_t)Mtot * Hh * 2;           // MLP hidden bf16
  if (region < mbytes) region = mbytes;
  if (off + region > ws_size) {                          // fallback: per-batch
    nbat = 1;
    region = mbytes;
  }
  char* reg = alloc(region);
  bf16* attn = (bf16*)reg;
  bf16* mb = (bf16*)reg;  // aliases attn (used after attention done)

  const dim3 tb(32, 8);

  // weight prep (bf16, [N][K]); q/k/v stacked into wqkvT rows 0/768/1536
  transpose_w<<<dim3(D / 32, D / 32), tb, 0, stream>>>(Wq, wqkvT, D, D);
  transpose_w<<<dim3(D / 32, D / 32), tb, 0, stream>>>(Wk, wqkvT + (size_t)D * D, D, D);
  transpose_w<<<dim3(D / 32, D / 32), tb, 0, stream>>>(Wv, wqkvT + 2 * (size_t)D * D, D, D);
  transpose_w<<<dim3(D / 32, D / 32), tb, 0, stream>>>(Wo, woT, D, D);
  transpose_w<<<dim3(Hh / 32, D / 32), tb, 0, stream>>>(Wfc, wfcT, D, Hh);
  transpose_w<<<dim3(D / 32, Hh / 32), tb, 0, stream>>>(Wproj, wprT, Hh, D);
  concat3<<<3, 256, 0, stream>>>(bq, bk, bvv, bqkv);

  // LN1 -> h (bf16)
  ln_kernel<<<(int)Mtot, 256, 0, stream>>>(x, ln1g, ln1b, hb);

  // fused QKV projection: [16384,768] @ [2304,768]^T -> [16384,2304]
  gemm_bt<0><<<dim3(Mtot / 128, QKVN / 128, 1), 256, 0, stream>>>(
      hb, 0, D, wqkvT, 0, D, bqkv, nullptr, nullptr, 0, 0, qkv, 0, QKVN, D, 1.f);
  transpose_v<<<dim3(D / 32, S / 32, Bz), tb, 0, stream>>>(qkv, vtb);

  // attention: p = exp(QK^T*sc) (panel-16, partial sums) -> reduce -> PV/div
  const float sc = 0.03608439182435161f;  // 1/sqrt(768)
  for (int g0 = 0; g0 < Bz; g0 += nbat) {
    const bf16* qg  = qkv + (long)g0 * S * QKVN;          // q slice, lda=2304
    const bf16* kg  = qkv + (long)g0 * S * QKVN + D;      // k slice, ldb=2304
    const bf16* vtg = vtb + (long)g0 * D * S;
    float* rsg = rsum + (long)g0 * S;
    float* rpg = rpart + (long)g0 * S;
    bf16* yg = yb + (long)g0 * S * D;
    gemm_bt<6><<<dim3(S / 128, S / 128, nbat), 256, 0, stream>>>(
        qg, (long)S * QKVN, QKVN, kg, (long)S * QKVN, QKVN, nullptr, nullptr,
        rpg, S, Mtot, attn, (long)S * S, S, D, sc);
    reduce32<<<(int)(Mtot / 256), 256, 0, stream>>>(rpart, rsum, (int)Mtot);
    gemm_bt<5><<<dim3(S / 128, D / 128, nbat), 256, 0, stream>>>(
        attn, (long)S * S, S, vtg, (long)D * S, S, nullptr, nullptr,
        rsg, S, 0, yg, (long)S * D, D, S, 1.f);
  }

  // out-projection + residual -> d_out (fp32)
  gemm_bt<3><<<dim3(Mtot / 128, D / 128, 1), 256, 0, stream>>>(
      yb, 0, D, woT, 0, D, bo, x, nullptr, 0, 0, out, 0, D, D, 1.f);

  // LN2 -> h2 (bf16, reuse hb)
  ln_kernel<<<(int)Mtot, 256, 0, stream>>>(out, ln2g, ln2b, hb);

  // MLP: fc + exact GELU -> mb (bf16), then proj + residual (in-place on d_out)
  gemm_bt<4><<<dim3(Mtot / 128, Hh / 128, 1), 256, 0, stream>>>(
      hb, 0, D, wfcT, 0, D, bfc, nullptr, nullptr, 0, 0, mb, 0, Hh, D, 1.f);
  gemm_bt<3><<<dim3(Mtot / 128, D / 128, 1), 256, 0, stream>>>(
      mb, 0, Hh, wprT, 0, Hh, bproj, out, nullptr, 0, 0, out, 0, D, Hh, 1.f);
}

// Round 10
// 611.602 us; speedup vs baseline: 2.5284x; 1.0230x over previous
//
#include <hip/hip_runtime.h>
#include <hip/hip_bf16.h>

typedef __attribute__((ext_vector_type(8))) short short8;
typedef __attribute__((ext_vector_type(4))) float floatx4;

using bf16 = __hip_bfloat16;

__device__ __forceinline__ void cp16_g2l(bf16* lds_p, const bf16* g) {
  __builtin_amdgcn_global_load_lds(
      (const __attribute__((address_space(1))) unsigned int*)g,
      (__attribute__((address_space(3))) unsigned int*)lds_p,
      16, 0, 0);
}

__device__ __forceinline__ float gelu_exact(float x) {
  return 0.5f * x * (1.0f + erff(x * 0.70710678118654752f));
}

// ---------------------------------------------------------------------------
// 128x128 tile GEMM, BK=32, 4 waves, mfma_f32_16x16x32_bf16.
// Ring-3 LDS (48 KiB, 3 blocks/CU) + counted vmcnt(4) (r8).
// T1 XCD swizzle: block lid -> (lid&7)*(nwg/8) + (lid>>3); each XCD owns a
// contiguous chunk (scores: one batch -> 6.3MB Q+K per XCD L2).
// Requires gridDim product % 8 == 0 (all call sites satisfy).
// T2 swizzle (rule #21): 16B slot u of row r at physical u^((r>>1)&3).
// Panel-16 layout for P: elem(row,col) at (col>>4)*(PR*16)+row*16+(col&15),
// PR = P row count. MODE 6 writes panels with stride N*16 (N == PR at that
// call site -- r9 bug used lda*16 = wrong stride); MODE 5 stages A from
// panels with PR = lda.
// MODE 0: bf16 = acc + bias                      (QKV)
// MODE 4: bf16 = gelu(acc + bias)                (fc)
// MODE 5: bf16 = acc / rowsum                    (PV; A from panel-16;
//         rowsum via ones-MFMA accs[m][r]; fragment rows == writer rows)
// MODE 6: bf16 = exp(acc*scale) to panel-16      (scores)
// MODE 7: bf16 = acc + bias + f32 resid          (Wo -> bf16 x1)
// MODE 8: f32  = acc + bias + bf16 resid         (proj -> d_out)
// ---------------------------------------------------------------------------
template<int MODE>
__global__ __launch_bounds__(256)
void gemm_bt(const bf16* __restrict__ A, long sAb, long lda,
             const bf16* __restrict__ Bt, long sBb, long ldb,
             const float* __restrict__ bias,
             const float* __restrict__ residf,
             const bf16* __restrict__ residb,
             void* __restrict__ out, long sOb,
             int N, int K, float scale)
{
  constexpr bool PA   = (MODE == 5);   // A operand in panel-16 layout
  constexpr bool ONES = (MODE == 5);   // row-sum via ones-MFMA

  __shared__ __attribute__((aligned(16))) bf16 sA[3][128 * 32];
  __shared__ __attribute__((aligned(16))) bf16 sB[3][128 * 32];

  // ---- T1 XCD-aware remap of block ids (bijective; nwg % 8 == 0) ----------
  const int nwg = gridDim.x * gridDim.y * gridDim.z;
  int lid = blockIdx.x + gridDim.x * (blockIdx.y + gridDim.y * blockIdx.z);
  lid = (lid & 7) * (nwg >> 3) + (lid >> 3);
  const int bx = lid % gridDim.x;
  const int tmp = lid / gridDim.x;
  const int by = tmp % gridDim.y;
  const int bz = tmp / gridDim.y;

  const int tid = threadIdx.x;
  const int l = tid & 63, w = tid >> 6;
  const long row0 = (long)bx * 128;
  const long col0 = (long)by * 128;

  const bf16* Ab = A + (long)bz * sAb;
  const bf16* Bb = Bt + (long)bz * sBb;

  // staging: wave w covers rows [w*16,+16) and [+64); 4x 16B slots per row
  const int sr = (w << 4) + (l >> 2);                  // 0..63
  const int slot = (l & 3) ^ ((sr >> 1) & 3);          // inverse-swizzled src
  const int kcd = (l & 3) << 3;                        // lane-linear dest
  const bf16* gA;
  long skipA, koA;
  if constexpr (PA) {
    gA    = Ab + ((long)(slot >> 1) * lda + row0 + sr) * 16 + ((slot & 1) << 3);
    skipA = 64 * 16;          // +64 rows within a panel
    koA   = 32 * lda;         // per-K-step advance (2 panels)
  } else {
    gA    = Ab + (row0 + sr) * lda + (slot << 3);
    skipA = 64 * lda;
    koA   = 32;
  }
  const bf16* gB = Bb + (col0 + sr) * ldb + (slot << 3);
  const long skipB = 64 * ldb;
  const int lofs = sr * 32 + kcd;

  floatx4 acc[4][4];
  #pragma unroll
  for (int i = 0; i < 4; ++i)
    #pragma unroll
    for (int j = 0; j < 4; ++j)
      acc[i][j] = (floatx4){0.f, 0.f, 0.f, 0.f};
  floatx4 accs[4];
  #pragma unroll
  for (int i = 0; i < 4; ++i) accs[i] = (floatx4){0.f, 0.f, 0.f, 0.f};
  const short8 b_ones = {0x3F80, 0x3F80, 0x3F80, 0x3F80,
                         0x3F80, 0x3F80, 0x3F80, 0x3F80};  // bf16 1.0 x8

  const int wr = (w >> 1) & 1, wc = w & 1;
  const int g = l >> 4, t = l & 15;
  const int swz = (g ^ ((t >> 1) & 3)) << 3;           // swizzled ds_read slot
  const int aoff = (wr * 64 + t) * 32 + swz;
  const int boff = (wc * 64 + t) * 32 + swz;

  const int nt = K >> 5;

  // prologue: stage tile 0 into buf 0 (4 loads in flight)
  cp16_g2l(&sA[0][lofs],           gA);
  cp16_g2l(&sA[0][lofs] + 64 * 32, gA + skipA);
  cp16_g2l(&sB[0][lofs],           gB);
  cp16_g2l(&sB[0][lofs] + 64 * 32, gB + skipB);

  int bufc = 0;
  for (int kt = 0; kt < nt; ++kt) {
    const int nxtb = (bufc == 2) ? 0 : bufc + 1;
    if (kt + 1 < nt) {
      const long oA = (long)(kt + 1) * koA;
      const long oB = (long)(kt + 1) << 5;
      cp16_g2l(&sA[nxtb][lofs],           gA + oA);
      cp16_g2l(&sA[nxtb][lofs] + 64 * 32, gA + oA + skipA);
      cp16_g2l(&sB[nxtb][lofs],           gB + oB);
      cp16_g2l(&sB[nxtb][lofs] + 64 * 32, gB + oB + skipB);
      asm volatile("s_waitcnt vmcnt(4)" ::: "memory");  // tile kt landed
    } else {
      asm volatile("s_waitcnt vmcnt(0)" ::: "memory");  // final tile landed
    }
    asm volatile("s_barrier" ::: "memory");             // all waves ready

    const bf16* cA = &sA[bufc][0];
    const bf16* cB = &sB[bufc][0];
    short8 a[4], b[4];
    #pragma unroll
    for (int m = 0; m < 4; ++m) a[m] = *(const short8*)(cA + aoff + m * 512);
    #pragma unroll
    for (int n = 0; n < 4; ++n) b[n] = *(const short8*)(cB + boff + n * 512);
    #pragma unroll
    for (int m = 0; m < 4; ++m)
      #pragma unroll
      for (int n = 0; n < 4; ++n)
        acc[m][n] = __builtin_amdgcn_mfma_f32_16x16x32_bf16(a[m], b[n], acc[m][n], 0, 0, 0);
    if constexpr (ONES) {
      #pragma unroll
      for (int m = 0; m < 4; ++m)
        accs[m] = __builtin_amdgcn_mfma_f32_16x16x32_bf16(a[m], b_ones, accs[m], 0, 0, 0);
    }
    bufc = nxtb;
  }

  // epilogue: C/D layout col = lane&15, row = (lane>>4)*4 + r  [m89]
  const long orow = row0 + wr * 64 + (g << 2);
  const long ocol = col0 + wc * 64 + t;

  if constexpr (MODE == 0 || MODE == 4) {
    bf16* O = (bf16*)out + (long)bz * sOb;
    float bv4[4];
    #pragma unroll
    for (int n = 0; n < 4; ++n) bv4[n] = bias[ocol + n * 16];
    #pragma unroll
    for (int m = 0; m < 4; ++m) {
      #pragma unroll
      for (int r = 0; r < 4; ++r) {
        bf16* Or = O + (orow + m * 16 + r) * (long)N + ocol;
        #pragma unroll
        for (int n = 0; n < 4; ++n) {      // n innermost: row-dense stores
          float vv = acc[m][n][r] + bv4[n];
          if constexpr (MODE == 4) vv = gelu_exact(vv);
          Or[n * 16] = __float2bfloat16(vv);
        }
      }
    }
  } else if constexpr (MODE == 7) {        // bf16 = acc + bias + f32 resid
    bf16* O = (bf16*)out;
    float bv4[4];
    #pragma unroll
    for (int n = 0; n < 4; ++n) bv4[n] = bias[ocol + n * 16];
    #pragma unroll
    for (int m = 0; m < 4; ++m) {
      #pragma unroll
      for (int r = 0; r < 4; ++r) {
        const long rb = (orow + m * 16 + r) * (long)N + ocol;
        #pragma unroll
        for (int n = 0; n < 4; ++n)
          O[rb + n * 16] =
              __float2bfloat16(acc[m][n][r] + bv4[n] + residf[rb + n * 16]);
      }
    }
  } else if constexpr (MODE == 8) {        // f32 = acc + bias + bf16 resid
    float* O = (float*)out;
    float bv4[4];
    #pragma unroll
    for (int n = 0; n < 4; ++n) bv4[n] = bias[ocol + n * 16];
    #pragma unroll
    for (int m = 0; m < 4; ++m) {
      #pragma unroll
      for (int r = 0; r < 4; ++r) {
        const long rb = (orow + m * 16 + r) * (long)N + ocol;
        #pragma unroll
        for (int n = 0; n < 4; ++n)
          O[rb + n * 16] = acc[m][n][r] + bv4[n] +
                           __bfloat162float(residb[rb + n * 16]);
      }
    }
  } else if constexpr (MODE == 5) {
    bf16* O = (bf16*)out + (long)bz * sOb;
    #pragma unroll
    for (int m = 0; m < 4; ++m) {
      #pragma unroll
      for (int r = 0; r < 4; ++r) {
        const long rr = orow + m * 16 + r;
        const float inv = 1.0f / accs[m][r];   // ones-MFMA row sum (exact
        bf16* Or = O + rr * (long)N + ocol;    // same rows as this lane)
        #pragma unroll
        for (int n = 0; n < 4; ++n)
          Or[n * 16] = __float2bfloat16(acc[m][n][r] * inv);
      }
    }
  } else {  // MODE 6: panel-16 exp output; panel stride = N*16 (N == P rows)
    bf16* O = (bf16*)out + (long)bz * sOb;
    const long pb = (col0 >> 4) + wc * 4;              // panel index base
    #pragma unroll
    for (int n = 0; n < 4; ++n) {                      // n outer: panel-dense
      bf16* Opan = O + (pb + n) * ((long)N * 16) + t;
      #pragma unroll
      for (int m = 0; m < 4; ++m) {
        #pragma unroll
        for (int r = 0; r < 4; ++r)
          Opan[(orow + m * 16 + r) * 16] =
              __float2bfloat16(__expf(acc[m][n][r] * scale));
      }
    }
  }
}

// row LayerNorm over D=768, fp32 in -> bf16 out
__global__ __launch_bounds__(256)
void ln_kernel(const float* __restrict__ X, const float* __restrict__ G,
               const float* __restrict__ Bv, bf16* __restrict__ H)
{
  const int tid = threadIdx.x;
  const long row = blockIdx.x;
  const float* xr = X + row * 768;
  const float v0 = xr[tid], v1 = xr[tid + 256], v2 = xr[tid + 512];
  float s = v0 + v1 + v2;
  float s2 = v0 * v0 + v1 * v1 + v2 * v2;
  #pragma unroll
  for (int o = 32; o > 0; o >>= 1) {
    s += __shfl_xor(s, o);
    s2 += __shfl_xor(s2, o);
  }
  __shared__ float red[8];
  const int w = tid >> 6, l = tid & 63;
  if (l == 0) { red[w] = s; red[w + 4] = s2; }
  __syncthreads();
  s = red[0] + red[1] + red[2] + red[3];
  s2 = red[4] + red[5] + red[6] + red[7];
  const float mu = s * (1.f / 768.f);
  const float var = s2 * (1.f / 768.f) - mu * mu;
  const float rstd = rsqrtf(var + 1e-5f);
  bf16* hr = H + row * 768;
  hr[tid]       = __float2bfloat16((v0 - mu) * rstd * G[tid]       + Bv[tid]);
  hr[tid + 256] = __float2bfloat16((v1 - mu) * rstd * G[tid + 256] + Bv[tid + 256]);
  hr[tid + 512] = __float2bfloat16((v2 - mu) * rstd * G[tid + 512] + Bv[tid + 512]);
}

// row LayerNorm over D=768, bf16 in -> bf16 out
__global__ __launch_bounds__(256)
void lnb_kernel(const bf16* __restrict__ X, const float* __restrict__ G,
                const float* __restrict__ Bv, bf16* __restrict__ H)
{
  const int tid = threadIdx.x;
  const long row = blockIdx.x;
  const bf16* xr = X + row * 768;
  const float v0 = __bfloat162float(xr[tid]);
  const float v1 = __bfloat162float(xr[tid + 256]);
  const float v2 = __bfloat162float(xr[tid + 512]);
  float s = v0 + v1 + v2;
  float s2 = v0 * v0 + v1 * v1 + v2 * v2;
  #pragma unroll
  for (int o = 32; o > 0; o >>= 1) {
    s += __shfl_xor(s, o);
    s2 += __shfl_xor(s2, o);
  }
  __shared__ float red[8];
  const int w = tid >> 6, l = tid & 63;
  if (l == 0) { red[w] = s; red[w + 4] = s2; }
  __syncthreads();
  s = red[0] + red[1] + red[2] + red[3];
  s2 = red[4] + red[5] + red[6] + red[7];
  const float mu = s * (1.f / 768.f);
  const float var = s2 * (1.f / 768.f) - mu * mu;
  const float rstd = rsqrtf(var + 1e-5f);
  bf16* hr = H + row * 768;
  hr[tid]       = __float2bfloat16((v0 - mu) * rstd * G[tid]       + Bv[tid]);
  hr[tid + 256] = __float2bfloat16((v1 - mu) * rstd * G[tid + 256] + Bv[tid + 256]);
  hr[tid + 512] = __float2bfloat16((v2 - mu) * rstd * G[tid + 512] + Bv[tid + 512]);
}

// Wt[n][k] = bf16(W[k][n]) ; W fp32 [K][N]. block (32,8)
__global__ void transpose_w(const float* __restrict__ W, bf16* __restrict__ Wt,
                            int K, int N)
{
  __shared__ float tile[32][33];
  const int n0 = blockIdx.x * 32, k0 = blockIdx.y * 32;
  const int tx = threadIdx.x, ty = threadIdx.y;
  #pragma unroll
  for (int j = ty; j < 32; j += 8)
    tile[j][tx] = W[(long)(k0 + j) * N + n0 + tx];
  __syncthreads();
  #pragma unroll
  for (int j = ty; j < 32; j += 8)
    Wt[(long)(n0 + j) * K + k0 + tx] = __float2bfloat16(tile[tx][j]);
}

// Vt[b][d][s] = qkv[(b*2048+s)*2304 + 1536 + d]  (bf16 v-slice of fused qkv)
__global__ void transpose_v(const bf16* __restrict__ QKV, bf16* __restrict__ Vt)
{
  __shared__ bf16 tile[32][33];
  const int d0 = blockIdx.x * 32, s0 = blockIdx.y * 32, b = blockIdx.z;
  const int tx = threadIdx.x, ty = threadIdx.y;
  #pragma unroll
  for (int j = ty; j < 32; j += 8)
    tile[j][tx] = QKV[((long)b * 2048 + s0 + j) * 2304 + 1536 + d0 + tx];
  __syncthreads();
  #pragma unroll
  for (int j = ty; j < 32; j += 8)
    Vt[(long)b * 768 * 2048 + (long)(d0 + j) * 2048 + s0 + tx] = tile[tx][j];
}

// concat 3x768 fp32 biases
__global__ void concat3(const float* __restrict__ a, const float* __restrict__ b,
                        const float* __restrict__ c, float* __restrict__ o)
{
  const int i = threadIdx.x + blockIdx.x * 256;
  if (i < 768) { o[i] = a[i]; o[i + 768] = b[i]; o[i + 1536] = c[i]; }
}

extern "C" void kernel_launch(void* const* d_in, const int* in_sizes, int n_in,
                              void* d_out, int out_size, void* d_ws, size_t ws_size,
                              hipStream_t stream)
{
  const float* x     = (const float*)d_in[0];
  const float* ln1g  = (const float*)d_in[1];
  const float* ln1b  = (const float*)d_in[2];
  const float* ln2g  = (const float*)d_in[3];
  const float* ln2b  = (const float*)d_in[4];
  const float* Wq    = (const float*)d_in[5];
  const float* bq    = (const float*)d_in[6];
  const float* Wk    = (const float*)d_in[7];
  const float* bk    = (const float*)d_in[8];
  const float* Wv    = (const float*)d_in[9];
  const float* bvv   = (const float*)d_in[10];
  const float* Wo    = (const float*)d_in[11];
  const float* bo    = (const float*)d_in[12];
  const float* Wfc   = (const float*)d_in[13];
  const float* bfc   = (const float*)d_in[14];
  const float* Wproj = (const float*)d_in[15];
  const float* bproj = (const float*)d_in[16];
  float* out = (float*)d_out;

  constexpr int Bz = 8, S = 2048, D = 768, Hh = 3072, QKVN = 3 * D;
  constexpr long Mtot = (long)Bz * S;  // 16384

  char* ws = (char*)d_ws;
  size_t off = 0;
  auto alloc = [&](size_t bytes) -> char* {
    char* p = ws + off;
    off += (bytes + 255) & ~(size_t)255;
    return p;
  };
  bf16* wqkvT = (bf16*)alloc((size_t)QKVN * D * 2);
  bf16* woT   = (bf16*)alloc((size_t)D * D * 2);
  bf16* wfcT  = (bf16*)alloc((size_t)Hh * D * 2);
  bf16* wprT  = (bf16*)alloc((size_t)D * Hh * 2);
  float* bqkv = (float*)alloc((size_t)QKVN * 4);
  bf16* hb    = (bf16*)alloc((size_t)Mtot * D * 2);
  bf16* qkv   = (bf16*)alloc((size_t)Mtot * QKVN * 2);
  bf16* vtb   = (bf16*)alloc((size_t)Mtot * D * 2);
  bf16* yb    = (bf16*)alloc((size_t)Mtot * D * 2);
  // x1 (bf16 residual stream) ALIASES qkv: qkv is dead after the last scores
  // GEMM; Wo (which writes x1) launches strictly after it. No new ws demand
  // (r9's fault was +25MB x1b overflowing ws_size).
  bf16* x1b = qkv;

  int nbat = Bz;
  size_t region = (size_t)nbat * S * S * 2;              // p (bf16, panel-16)
  const size_t mbytes = (size_t)Mtot * Hh * 2;           // MLP hidden bf16
  if (region < mbytes) region = mbytes;
  if (off + region > ws_size) {                          // fallback: per-batch
    nbat = 1;
    region = mbytes;
  }
  char* reg = alloc(region);
  bf16* attn = (bf16*)reg;
  bf16* mb = (bf16*)reg;  // aliases attn (used after attention done)

  const dim3 tb(32, 8);

  // weight prep (bf16, [N][K]); q/k/v stacked into wqkvT rows 0/768/1536
  transpose_w<<<dim3(D / 32, D / 32), tb, 0, stream>>>(Wq, wqkvT, D, D);
  transpose_w<<<dim3(D / 32, D / 32), tb, 0, stream>>>(Wk, wqkvT + (size_t)D * D, D, D);
  transpose_w<<<dim3(D / 32, D / 32), tb, 0, stream>>>(Wv, wqkvT + 2 * (size_t)D * D, D, D);
  transpose_w<<<dim3(D / 32, D / 32), tb, 0, stream>>>(Wo, woT, D, D);
  transpose_w<<<dim3(Hh / 32, D / 32), tb, 0, stream>>>(Wfc, wfcT, D, Hh);
  transpose_w<<<dim3(D / 32, Hh / 32), tb, 0, stream>>>(Wproj, wprT, Hh, D);
  concat3<<<3, 256, 0, stream>>>(bq, bk, bvv, bqkv);

  // LN1 -> h (bf16)
  ln_kernel<<<(int)Mtot, 256, 0, stream>>>(x, ln1g, ln1b, hb);

  // fused QKV projection: [16384,768] @ [2304,768]^T -> [16384,2304]
  gemm_bt<0><<<dim3(Mtot / 128, QKVN / 128, 1), 256, 0, stream>>>(
      hb, 0, D, wqkvT, 0, D, bqkv, nullptr, nullptr, qkv, 0, QKVN, D, 1.f);
  transpose_v<<<dim3(D / 32, S / 32, Bz), tb, 0, stream>>>(qkv, vtb);

  // attention: p = exp(QK^T*sc) (panel-16) -> PV with ones-MFMA row-sums
  const float sc = 0.03608439182435161f;  // 1/sqrt(768)
  for (int g0 = 0; g0 < Bz; g0 += nbat) {
    const bf16* qg  = qkv + (long)g0 * S * QKVN;          // q slice, lda=2304
    const bf16* kg  = qkv + (long)g0 * S * QKVN + D;      // k slice, ldb=2304
    const bf16* vtg = vtb + (long)g0 * D * S;
    bf16* yg = yb + (long)g0 * S * D;
    gemm_bt<6><<<dim3(S / 128, S / 128, nbat), 256, 0, stream>>>(
        qg, (long)S * QKVN, QKVN, kg, (long)S * QKVN, QKVN, nullptr, nullptr,
        nullptr, attn, (long)S * S, S, D, sc);
    gemm_bt<5><<<dim3(S / 128, D / 128, nbat), 256, 0, stream>>>(
        attn, (long)S * S, S, vtg, (long)D * S, S, nullptr, nullptr,
        nullptr, yg, (long)S * D, D, S, 1.f);
  }

  // out-projection + residual -> x1 (bf16 residual stream, aliases dead qkv)
  gemm_bt<7><<<dim3(Mtot / 128, D / 128, 1), 256, 0, stream>>>(
      yb, 0, D, woT, 0, D, bo, x, nullptr, x1b, 0, D, D, 1.f);

  // LN2 -> h2 (bf16, reuse hb)
  lnb_kernel<<<(int)Mtot, 256, 0, stream>>>(x1b, ln2g, ln2b, hb);

  // MLP: fc + exact GELU -> mb (bf16), then proj + bf16 resid -> f32 d_out
  gemm_bt<4><<<dim3(Mtot / 128, Hh / 128, 1), 256, 0, stream>>>(
      hb, 0, D, wfcT, 0, D, bfc, nullptr, nullptr, mb, 0, Hh, D, 1.f);
  gemm_bt<8><<<dim3(Mtot / 128, D / 128, 1), 256, 0, stream>>>(
      mb, 0, Hh, wprT, 0, Hh, bproj, nullptr, x1b, out, 0, D, Hh, 1.f);
}

// Round 11
// 555.118 us; speedup vs baseline: 2.7857x; 1.1018x over previous
//
#include <hip/hip_runtime.h>
#include <hip/hip_bf16.h>

typedef __attribute__((ext_vector_type(8))) short short8;
typedef __attribute__((ext_vector_type(4))) float floatx4;

using bf16 = __hip_bfloat16;

__device__ __forceinline__ void cp16_g2l(bf16* lds_p, const bf16* g) {
  __builtin_amdgcn_global_load_lds(
      (const __attribute__((address_space(1))) unsigned int*)g,
      (__attribute__((address_space(3))) unsigned int*)lds_p,
      16, 0, 0);
}

__device__ __forceinline__ float gelu_exact(float x) {
  return 0.5f * x * (1.0f + erff(x * 0.70710678118654752f));
}

// ---------------------------------------------------------------------------
// 128x128 tile GEMM, BK=32, 4 waves, mfma_f32_16x16x32_bf16.
// Ring-3 LDS (48 KiB, 3 blocks/CU) + counted vmcnt(4) (r8).
// NO XCD swizzle: r10 measured it 4.3x'd scores FETCH (70->300MB) -- the
// per-XCD contiguous chunk cycles a >4MiB Q+K working set through the 4MiB
// L2 and thrashes; default round-robin keeps co-issued blocks sharing the
// B panel. Natural blockIdx restored.
// T2 swizzle (rule #21): 16B slot u of row r at physical u^((r>>1)&3).
// Panel-16 layout for P: elem(row,col) at (col>>4)*(PR*16)+row*16+(col&15),
// PR = P row count. MODE 6 writes panels with stride N*16 (N == PR there);
// MODE 5 stages A from panels with PR = lda.
// MODE 0: bf16 = acc + bias                      (QKV)
// MODE 4: bf16 = gelu(acc + bias)                (fc)
// MODE 5: bf16 = acc / rowsum                    (PV; A from panel-16;
//         rowsum via ones-MFMA accs[m][r]; fragment rows == writer rows)
// MODE 6: bf16 = exp(acc*scale) to panel-16      (scores)
// MODE 7: bf16 = acc + bias + f32 resid          (Wo -> bf16 x1)
// MODE 8: f32  = acc + bias + bf16 resid         (proj -> d_out)
// ---------------------------------------------------------------------------
template<int MODE>
__global__ __launch_bounds__(256)
void gemm_bt(const bf16* __restrict__ A, long sAb, long lda,
             const bf16* __restrict__ Bt, long sBb, long ldb,
             const float* __restrict__ bias,
             const float* __restrict__ residf,
             const bf16* __restrict__ residb,
             void* __restrict__ out, long sOb,
             int N, int K, float scale)
{
  constexpr bool PA   = (MODE == 5);   // A operand in panel-16 layout
  constexpr bool ONES = (MODE == 5);   // row-sum via ones-MFMA

  __shared__ __attribute__((aligned(16))) bf16 sA[3][128 * 32];
  __shared__ __attribute__((aligned(16))) bf16 sB[3][128 * 32];

  const int tid = threadIdx.x;
  const int l = tid & 63, w = tid >> 6;
  const int bz = blockIdx.z;
  const long row0 = (long)blockIdx.x * 128;
  const long col0 = (long)blockIdx.y * 128;

  const bf16* Ab = A + (long)bz * sAb;
  const bf16* Bb = Bt + (long)bz * sBb;

  // staging: wave w covers rows [w*16,+16) and [+64); 4x 16B slots per row
  const int sr = (w << 4) + (l >> 2);                  // 0..63
  const int slot = (l & 3) ^ ((sr >> 1) & 3);          // inverse-swizzled src
  const int kcd = (l & 3) << 3;                        // lane-linear dest
  const bf16* gA;
  long skipA, koA;
  if constexpr (PA) {
    gA    = Ab + ((long)(slot >> 1) * lda + row0 + sr) * 16 + ((slot & 1) << 3);
    skipA = 64 * 16;          // +64 rows within a panel
    koA   = 32 * lda;         // per-K-step advance (2 panels)
  } else {
    gA    = Ab + (row0 + sr) * lda + (slot << 3);
    skipA = 64 * lda;
    koA   = 32;
  }
  const bf16* gB = Bb + (col0 + sr) * ldb + (slot << 3);
  const long skipB = 64 * ldb;
  const int lofs = sr * 32 + kcd;

  floatx4 acc[4][4];
  #pragma unroll
  for (int i = 0; i < 4; ++i)
    #pragma unroll
    for (int j = 0; j < 4; ++j)
      acc[i][j] = (floatx4){0.f, 0.f, 0.f, 0.f};
  floatx4 accs[4];
  #pragma unroll
  for (int i = 0; i < 4; ++i) accs[i] = (floatx4){0.f, 0.f, 0.f, 0.f};
  const short8 b_ones = {0x3F80, 0x3F80, 0x3F80, 0x3F80,
                         0x3F80, 0x3F80, 0x3F80, 0x3F80};  // bf16 1.0 x8

  const int wr = (w >> 1) & 1, wc = w & 1;
  const int g = l >> 4, t = l & 15;
  const int swz = (g ^ ((t >> 1) & 3)) << 3;           // swizzled ds_read slot
  const int aoff = (wr * 64 + t) * 32 + swz;
  const int boff = (wc * 64 + t) * 32 + swz;

  const int nt = K >> 5;

  // prologue: stage tile 0 into buf 0 (4 loads in flight)
  cp16_g2l(&sA[0][lofs],           gA);
  cp16_g2l(&sA[0][lofs] + 64 * 32, gA + skipA);
  cp16_g2l(&sB[0][lofs],           gB);
  cp16_g2l(&sB[0][lofs] + 64 * 32, gB + skipB);

  int bufc = 0;
  for (int kt = 0; kt < nt; ++kt) {
    const int nxtb = (bufc == 2) ? 0 : bufc + 1;
    if (kt + 1 < nt) {
      const long oA = (long)(kt + 1) * koA;
      const long oB = (long)(kt + 1) << 5;
      cp16_g2l(&sA[nxtb][lofs],           gA + oA);
      cp16_g2l(&sA[nxtb][lofs] + 64 * 32, gA + oA + skipA);
      cp16_g2l(&sB[nxtb][lofs],           gB + oB);
      cp16_g2l(&sB[nxtb][lofs] + 64 * 32, gB + oB + skipB);
      asm volatile("s_waitcnt vmcnt(4)" ::: "memory");  // tile kt landed
    } else {
      asm volatile("s_waitcnt vmcnt(0)" ::: "memory");  // final tile landed
    }
    asm volatile("s_barrier" ::: "memory");             // all waves ready

    const bf16* cA = &sA[bufc][0];
    const bf16* cB = &sB[bufc][0];
    short8 a[4], b[4];
    #pragma unroll
    for (int m = 0; m < 4; ++m) a[m] = *(const short8*)(cA + aoff + m * 512);
    #pragma unroll
    for (int n = 0; n < 4; ++n) b[n] = *(const short8*)(cB + boff + n * 512);
    #pragma unroll
    for (int m = 0; m < 4; ++m)
      #pragma unroll
      for (int n = 0; n < 4; ++n)
        acc[m][n] = __builtin_amdgcn_mfma_f32_16x16x32_bf16(a[m], b[n], acc[m][n], 0, 0, 0);
    if constexpr (ONES) {
      #pragma unroll
      for (int m = 0; m < 4; ++m)
        accs[m] = __builtin_amdgcn_mfma_f32_16x16x32_bf16(a[m], b_ones, accs[m], 0, 0, 0);
    }
    bufc = nxtb;
  }

  // epilogue: C/D layout col = lane&15, row = (lane>>4)*4 + r  [m89]
  const long orow = row0 + wr * 64 + (g << 2);
  const long ocol = col0 + wc * 64 + t;

  if constexpr (MODE == 0 || MODE == 4) {
    bf16* O = (bf16*)out + (long)bz * sOb;
    float bv4[4];
    #pragma unroll
    for (int n = 0; n < 4; ++n) bv4[n] = bias[ocol + n * 16];
    #pragma unroll
    for (int m = 0; m < 4; ++m) {
      #pragma unroll
      for (int r = 0; r < 4; ++r) {
        bf16* Or = O + (orow + m * 16 + r) * (long)N + ocol;
        #pragma unroll
        for (int n = 0; n < 4; ++n) {      // n innermost: row-dense stores
          float vv = acc[m][n][r] + bv4[n];
          if constexpr (MODE == 4) vv = gelu_exact(vv);
          Or[n * 16] = __float2bfloat16(vv);
        }
      }
    }
  } else if constexpr (MODE == 7) {        // bf16 = acc + bias + f32 resid
    bf16* O = (bf16*)out;
    float bv4[4];
    #pragma unroll
    for (int n = 0; n < 4; ++n) bv4[n] = bias[ocol + n * 16];
    #pragma unroll
    for (int m = 0; m < 4; ++m) {
      #pragma unroll
      for (int r = 0; r < 4; ++r) {
        const long rb = (orow + m * 16 + r) * (long)N + ocol;
        #pragma unroll
        for (int n = 0; n < 4; ++n)
          O[rb + n * 16] =
              __float2bfloat16(acc[m][n][r] + bv4[n] + residf[rb + n * 16]);
      }
    }
  } else if constexpr (MODE == 8) {        // f32 = acc + bias + bf16 resid
    float* O = (float*)out;
    float bv4[4];
    #pragma unroll
    for (int n = 0; n < 4; ++n) bv4[n] = bias[ocol + n * 16];
    #pragma unroll
    for (int m = 0; m < 4; ++m) {
      #pragma unroll
      for (int r = 0; r < 4; ++r) {
        const long rb = (orow + m * 16 + r) * (long)N + ocol;
        #pragma unroll
        for (int n = 0; n < 4; ++n)
          O[rb + n * 16] = acc[m][n][r] + bv4[n] +
                           __bfloat162float(residb[rb + n * 16]);
      }
    }
  } else if constexpr (MODE == 5) {
    bf16* O = (bf16*)out + (long)bz * sOb;
    #pragma unroll
    for (int m = 0; m < 4; ++m) {
      #pragma unroll
      for (int r = 0; r < 4; ++r) {
        const long rr = orow + m * 16 + r;
        const float inv = 1.0f / accs[m][r];   // ones-MFMA row sum (exact
        bf16* Or = O + rr * (long)N + ocol;    // same rows as this lane)
        #pragma unroll
        for (int n = 0; n < 4; ++n)
          Or[n * 16] = __float2bfloat16(acc[m][n][r] * inv);
      }
    }
  } else {  // MODE 6: panel-16 exp output; panel stride = N*16 (N == P rows)
    bf16* O = (bf16*)out + (long)bz * sOb;
    const long pb = (col0 >> 4) + wc * 4;              // panel index base
    #pragma unroll
    for (int n = 0; n < 4; ++n) {                      // n outer: panel-dense
      bf16* Opan = O + (pb + n) * ((long)N * 16) + t;
      #pragma unroll
      for (int m = 0; m < 4; ++m) {
        #pragma unroll
        for (int r = 0; r < 4; ++r)
          Opan[(orow + m * 16 + r) * 16] =
              __float2bfloat16(__expf(acc[m][n][r] * scale));
      }
    }
  }
}

// row LayerNorm over D=768, fp32 in -> bf16 out
__global__ __launch_bounds__(256)
void ln_kernel(const float* __restrict__ X, const float* __restrict__ G,
               const float* __restrict__ Bv, bf16* __restrict__ H)
{
  const int tid = threadIdx.x;
  const long row = blockIdx.x;
  const float* xr = X + row * 768;
  const float v0 = xr[tid], v1 = xr[tid + 256], v2 = xr[tid + 512];
  float s = v0 + v1 + v2;
  float s2 = v0 * v0 + v1 * v1 + v2 * v2;
  #pragma unroll
  for (int o = 32; o > 0; o >>= 1) {
    s += __shfl_xor(s, o);
    s2 += __shfl_xor(s2, o);
  }
  __shared__ float red[8];
  const int w = tid >> 6, l = tid & 63;
  if (l == 0) { red[w] = s; red[w + 4] = s2; }
  __syncthreads();
  s = red[0] + red[1] + red[2] + red[3];
  s2 = red[4] + red[5] + red[6] + red[7];
  const float mu = s * (1.f / 768.f);
  const float var = s2 * (1.f / 768.f) - mu * mu;
  const float rstd = rsqrtf(var + 1e-5f);
  bf16* hr = H + row * 768;
  hr[tid]       = __float2bfloat16((v0 - mu) * rstd * G[tid]       + Bv[tid]);
  hr[tid + 256] = __float2bfloat16((v1 - mu) * rstd * G[tid + 256] + Bv[tid + 256]);
  hr[tid + 512] = __float2bfloat16((v2 - mu) * rstd * G[tid + 512] + Bv[tid + 512]);
}

// row LayerNorm over D=768, bf16 in -> bf16 out
__global__ __launch_bounds__(256)
void lnb_kernel(const bf16* __restrict__ X, const float* __restrict__ G,
                const float* __restrict__ Bv, bf16* __restrict__ H)
{
  const int tid = threadIdx.x;
  const long row = blockIdx.x;
  const bf16* xr = X + row * 768;
  const float v0 = __bfloat162float(xr[tid]);
  const float v1 = __bfloat162float(xr[tid + 256]);
  const float v2 = __bfloat162float(xr[tid + 512]);
  float s = v0 + v1 + v2;
  float s2 = v0 * v0 + v1 * v1 + v2 * v2;
  #pragma unroll
  for (int o = 32; o > 0; o >>= 1) {
    s += __shfl_xor(s, o);
    s2 += __shfl_xor(s2, o);
  }
  __shared__ float red[8];
  const int w = tid >> 6, l = tid & 63;
  if (l == 0) { red[w] = s; red[w + 4] = s2; }
  __syncthreads();
  s = red[0] + red[1] + red[2] + red[3];
  s2 = red[4] + red[5] + red[6] + red[7];
  const float mu = s * (1.f / 768.f);
  const float var = s2 * (1.f / 768.f) - mu * mu;
  const float rstd = rsqrtf(var + 1e-5f);
  bf16* hr = H + row * 768;
  hr[tid]       = __float2bfloat16((v0 - mu) * rstd * G[tid]       + Bv[tid]);
  hr[tid + 256] = __float2bfloat16((v1 - mu) * rstd * G[tid + 256] + Bv[tid + 256]);
  hr[tid + 512] = __float2bfloat16((v2 - mu) * rstd * G[tid + 512] + Bv[tid + 512]);
}

// Wt[n][k] = bf16(W[k][n]) ; W fp32 [K][N]. block (32,8)
__global__ void transpose_w(const float* __restrict__ W, bf16* __restrict__ Wt,
                            int K, int N)
{
  __shared__ float tile[32][33];
  const int n0 = blockIdx.x * 32, k0 = blockIdx.y * 32;
  const int tx = threadIdx.x, ty = threadIdx.y;
  #pragma unroll
  for (int j = ty; j < 32; j += 8)
    tile[j][tx] = W[(long)(k0 + j) * N + n0 + tx];
  __syncthreads();
  #pragma unroll
  for (int j = ty; j < 32; j += 8)
    Wt[(long)(n0 + j) * K + k0 + tx] = __float2bfloat16(tile[tx][j]);
}

// Vt[b][d][s] = qkv[(b*2048+s)*2304 + 1536 + d]  (bf16 v-slice of fused qkv)
__global__ void transpose_v(const bf16* __restrict__ QKV, bf16* __restrict__ Vt)
{
  __shared__ bf16 tile[32][33];
  const int d0 = blockIdx.x * 32, s0 = blockIdx.y * 32, b = blockIdx.z;
  const int tx = threadIdx.x, ty = threadIdx.y;
  #pragma unroll
  for (int j = ty; j < 32; j += 8)
    tile[j][tx] = QKV[((long)b * 2048 + s0 + j) * 2304 + 1536 + d0 + tx];
  __syncthreads();
  #pragma unroll
  for (int j = ty; j < 32; j += 8)
    Vt[(long)b * 768 * 2048 + (long)(d0 + j) * 2048 + s0 + tx] = tile[tx][j];
}

// concat 3x768 fp32 biases
__global__ void concat3(const float* __restrict__ a, const float* __restrict__ b,
                        const float* __restrict__ c, float* __restrict__ o)
{
  const int i = threadIdx.x + blockIdx.x * 256;
  if (i < 768) { o[i] = a[i]; o[i + 768] = b[i]; o[i + 1536] = c[i]; }
}

extern "C" void kernel_launch(void* const* d_in, const int* in_sizes, int n_in,
                              void* d_out, int out_size, void* d_ws, size_t ws_size,
                              hipStream_t stream)
{
  const float* x     = (const float*)d_in[0];
  const float* ln1g  = (const float*)d_in[1];
  const float* ln1b  = (const float*)d_in[2];
  const float* ln2g  = (const float*)d_in[3];
  const float* ln2b  = (const float*)d_in[4];
  const float* Wq    = (const float*)d_in[5];
  const float* bq    = (const float*)d_in[6];
  const float* Wk    = (const float*)d_in[7];
  const float* bk    = (const float*)d_in[8];
  const float* Wv    = (const float*)d_in[9];
  const float* bvv   = (const float*)d_in[10];
  const float* Wo    = (const float*)d_in[11];
  const float* bo    = (const float*)d_in[12];
  const float* Wfc   = (const float*)d_in[13];
  const float* bfc   = (const float*)d_in[14];
  const float* Wproj = (const float*)d_in[15];
  const float* bproj = (const float*)d_in[16];
  float* out = (float*)d_out;

  constexpr int Bz = 8, S = 2048, D = 768, Hh = 3072, QKVN = 3 * D;
  constexpr long Mtot = (long)Bz * S;  // 16384

  char* ws = (char*)d_ws;
  size_t off = 0;
  auto alloc = [&](size_t bytes) -> char* {
    char* p = ws + off;
    off += (bytes + 255) & ~(size_t)255;
    return p;
  };
  bf16* wqkvT = (bf16*)alloc((size_t)QKVN * D * 2);
  bf16* woT   = (bf16*)alloc((size_t)D * D * 2);
  bf16* wfcT  = (bf16*)alloc((size_t)Hh * D * 2);
  bf16* wprT  = (bf16*)alloc((size_t)D * Hh * 2);
  float* bqkv = (float*)alloc((size_t)QKVN * 4);
  bf16* hb    = (bf16*)alloc((size_t)Mtot * D * 2);
  bf16* qkv   = (bf16*)alloc((size_t)Mtot * QKVN * 2);
  bf16* vtb   = (bf16*)alloc((size_t)Mtot * D * 2);
  bf16* yb    = (bf16*)alloc((size_t)Mtot * D * 2);
  // x1 (bf16 residual stream) ALIASES qkv: qkv is dead after the last scores
  // GEMM; Wo (which writes x1) launches strictly after it.
  bf16* x1b = qkv;

  int nbat = Bz;
  size_t region = (size_t)nbat * S * S * 2;              // p (bf16, panel-16)
  const size_t mbytes = (size_t)Mtot * Hh * 2;           // MLP hidden bf16
  if (region < mbytes) region = mbytes;
  if (off + region > ws_size) {                          // fallback: per-batch
    nbat = 1;
    region = mbytes;
  }
  char* reg = alloc(region);
  bf16* attn = (bf16*)reg;
  bf16* mb = (bf16*)reg;  // aliases attn (used after attention done)

  const dim3 tb(32, 8);

  // weight prep (bf16, [N][K]); q/k/v stacked into wqkvT rows 0/768/1536
  transpose_w<<<dim3(D / 32, D / 32), tb, 0, stream>>>(Wq, wqkvT, D, D);
  transpose_w<<<dim3(D / 32, D / 32), tb, 0, stream>>>(Wk, wqkvT + (size_t)D * D, D, D);
  transpose_w<<<dim3(D / 32, D / 32), tb, 0, stream>>>(Wv, wqkvT + 2 * (size_t)D * D, D, D);
  transpose_w<<<dim3(D / 32, D / 32), tb, 0, stream>>>(Wo, woT, D, D);
  transpose_w<<<dim3(Hh / 32, D / 32), tb, 0, stream>>>(Wfc, wfcT, D, Hh);
  transpose_w<<<dim3(D / 32, Hh / 32), tb, 0, stream>>>(Wproj, wprT, Hh, D);
  concat3<<<3, 256, 0, stream>>>(bq, bk, bvv, bqkv);

  // LN1 -> h (bf16)
  ln_kernel<<<(int)Mtot, 256, 0, stream>>>(x, ln1g, ln1b, hb);

  // fused QKV projection: [16384,768] @ [2304,768]^T -> [16384,2304]
  gemm_bt<0><<<dim3(Mtot / 128, QKVN / 128, 1), 256, 0, stream>>>(
      hb, 0, D, wqkvT, 0, D, bqkv, nullptr, nullptr, qkv, 0, QKVN, D, 1.f);
  transpose_v<<<dim3(D / 32, S / 32, Bz), tb, 0, stream>>>(qkv, vtb);

  // attention: p = exp(QK^T*sc) (panel-16) -> PV with ones-MFMA row-sums
  const float sc = 0.03608439182435161f;  // 1/sqrt(768)
  for (int g0 = 0; g0 < Bz; g0 += nbat) {
    const bf16* qg  = qkv + (long)g0 * S * QKVN;          // q slice, lda=2304
    const bf16* kg  = qkv + (long)g0 * S * QKVN + D;      // k slice, ldb=2304
    const bf16* vtg = vtb + (long)g0 * D * S;
    bf16* yg = yb + (long)g0 * S * D;
    gemm_bt<6><<<dim3(S / 128, S / 128, nbat), 256, 0, stream>>>(
        qg, (long)S * QKVN, QKVN, kg, (long)S * QKVN, QKVN, nullptr, nullptr,
        nullptr, attn, (long)S * S, S, D, sc);
    gemm_bt<5><<<dim3(S / 128, D / 128, nbat), 256, 0, stream>>>(
        attn, (long)S * S, S, vtg, (long)D * S, S, nullptr, nullptr,
        nullptr, yg, (long)S * D, D, S, 1.f);
  }

  // out-projection + residual -> x1 (bf16 residual stream, aliases dead qkv)
  gemm_bt<7><<<dim3(Mtot / 128, D / 128, 1), 256, 0, stream>>>(
      yb, 0, D, woT, 0, D, bo, x, nullptr, x1b, 0, D, D, 1.f);

  // LN2 -> h2 (bf16, reuse hb)
  lnb_kernel<<<(int)Mtot, 256, 0, stream>>>(x1b, ln2g, ln2b, hb);

  // MLP: fc + exact GELU -> mb (bf16), then proj + bf16 resid -> f32 d_out
  gemm_bt<4><<<dim3(Mtot / 128, Hh / 128, 1), 256, 0, stream>>>(
      hb, 0, D, wfcT, 0, D, bfc, nullptr, nullptr, mb, 0, Hh, D, 1.f);
  gemm_bt<8><<<dim3(Mtot / 128, D / 128, 1), 256, 0, stream>>>(
      mb, 0, Hh, wprT, 0, Hh, bproj, nullptr, x1b, out, 0, D, Hh, 1.f);
}